// Round 4
// baseline (1260.382 us; speedup 1.0000x reference)
//
#include <hip/hip_runtime.h>
#include <hip/hip_bf16.h>
#include <stdint.h>

#define DEV static __device__ __forceinline__

typedef float f32x4 __attribute__((ext_vector_type(4)));
typedef short bf16x8 __attribute__((ext_vector_type(8)));
typedef float accf4 __attribute__((ext_vector_type(4)));
typedef unsigned short u16;
typedef unsigned int u32;
typedef u16 u16x4 __attribute__((ext_vector_type(4)));

#define BB 4
#define TT 1024
#define DD 1024
#define HH 8
#define DKK 128
#define DVV 128
#define MM (BB*TT)
#define DFF 4096

DEV u16 f2b(float f){
  union { float f; u32 u; } v; v.f = f;
  u32 r = (v.u + 0x7fffu + ((v.u >> 16) & 1u)) >> 16;
  return (u16)r;
}
DEV float b2f(u16 h){
  union { u32 u; float f; } v; v.u = ((u32)h) << 16;
  return v.f;
}
DEV float sigm(float x){ return 1.f / (1.f + __expf(-x)); }
DEV float silu_f(float x){ return x / (1.f + __expf(-x)); }

DEV void gl_lds16(const void* g, void* l){
  __builtin_amdgcn_global_load_lds(
      (const __attribute__((address_space(1))) void*)g,
      (__attribute__((address_space(3))) void*)l, 16, 0, 0);
}

// ---- DPP cross-lane adds (VALU pipe, ~4cy latency each; no LDS traffic) ----
template<int CTRL>
DEV float dpp_add(float x){
  union { float f; int i; } u; u.f = x;
  int y = __builtin_amdgcn_update_dpp(0, u.i, CTRL, 0xf, 0xf, true);
  union { int i; float f; } w; w.i = y;
  return x + w.f;
}
// sum over 16-lane DPP row; all 16 lanes end with the full sum
DEV float red16(float x){
  x = dpp_add<0xB1>(x);  // quad_perm [1,0,3,2]  (xor 1)
  x = dpp_add<0x4E>(x);  // quad_perm [2,3,0,1]  (xor 2)
  x = dpp_add<0x141>(x); // row_half_mirror      (pairs 4-groups)
  x = dpp_add<0x140>(x); // row_mirror           (pairs 8-groups)
  return x;
}

// ---------------- GEMM: C[M,N] = A[M,K](bf16) * B[N,K](bf16)^T ---------------
// OP 0: C=acc(+bias)   OP 1: C+=acc   OP 2: Cb=bf16(silu(acc+bias))
// OP 3: Cb=bf16(silu(aux)*acc)
template<int OP>
__global__ __launch_bounds__(256) void gemm_bt(
    const u16* __restrict__ A, const u16* __restrict__ Bm,
    float* __restrict__ C, u16* __restrict__ Cb,
    const float* __restrict__ bias, const float* __restrict__ aux,
    int M, int N, int K)
{
  __shared__ u16 lsA[128*64];
  __shared__ u16 lsB[128*64];
  const int tid = threadIdx.x;
  const int bm = blockIdx.x, bn = blockIdx.y;
  const int wid = tid >> 6, lane = tid & 63;
  const int wr = wid >> 1, wc = wid & 1;
  const int fr = lane & 15, fq = lane >> 4;
  accf4 acc[4][4];
#pragma unroll
  for (int i=0;i<4;i++)
#pragma unroll
    for (int j=0;j<4;j++) acc[i][j] = (accf4)0.f;

  const int srow = tid >> 3;
  const int sk = (tid & 7) * 8;
  const u16* aP = A + (size_t)(bm*128 + srow) * K + sk;
  const u16* bP = Bm + (size_t)(bn*128 + srow) * K + sk;
  char* lA = (char*)lsA + tid*16;
  char* lB = (char*)lsB + tid*16;

  for (int kt = 0; kt < K; kt += 64) {
#pragma unroll
    for (int it=0; it<4; ++it) {
      gl_lds16(aP + (size_t)it*32*K + kt, lA + it*4096);
      gl_lds16(bP + (size_t)it*32*K + kt, lB + it*4096);
    }
    asm volatile("s_waitcnt vmcnt(0)" ::: "memory");
    __syncthreads();
#pragma unroll
    for (int ks=0; ks<2; ++ks) {
      bf16x8 av[4], bv[4];
#pragma unroll
      for (int i=0;i<4;i++)
        av[i] = *(const bf16x8*)&lsA[(wr*64 + i*16 + fr)*64 + ks*32 + fq*8];
#pragma unroll
      for (int j=0;j<4;j++)
        bv[j] = *(const bf16x8*)&lsB[(wc*64 + j*16 + fr)*64 + ks*32 + fq*8];
#pragma unroll
      for (int i=0;i<4;i++)
#pragma unroll
        for (int j=0;j<4;j++)
          acc[i][j] = __builtin_amdgcn_mfma_f32_16x16x32_bf16(av[i], bv[j], acc[i][j], 0, 0, 0);
    }
    __syncthreads();
  }

#pragma unroll
  for (int i=0;i<4;i++) {
    const int r0 = bm*128 + wr*64 + i*16 + fq*4;
#pragma unroll
    for (int j=0;j<4;j++) {
      const int c = bn*128 + wc*64 + j*16 + fr;
#pragma unroll
      for (int rr=0; rr<4; ++rr) {
        const size_t idx = (size_t)(r0+rr)*N + c;
        float v = acc[i][j][rr];
        if (OP == 0) { if (bias) v += bias[c]; C[idx] = v; }
        if (OP == 1) { C[idx] += v; }
        if (OP == 2) { v += bias[c]; Cb[idx] = f2b(silu_f(v)); }
        if (OP == 3) { Cb[idx] = f2b(silu_f(aux[idx]) * v); }
      }
    }
  }
}

// ---------------- conversions ----------------
__global__ void cvt_bf16(const float* __restrict__ s, u16* __restrict__ d, int n){
  int i = blockIdx.x*256 + threadIdx.x;
  if (i*4 < n) {
    f32x4 v = *(const f32x4*)(s + (size_t)i*4);
    u16x4 o; o.x=f2b(v.x); o.y=f2b(v.y); o.z=f2b(v.z); o.w=f2b(v.w);
    *(u16x4*)(d + (size_t)i*4) = o;
  }
}
__global__ void cvt_split(const float* __restrict__ s, u16* __restrict__ hi, u16* __restrict__ lo, int n){
  int i = blockIdx.x*256 + threadIdx.x;
  if (i*4 < n) {
    f32x4 v = *(const f32x4*)(s + (size_t)i*4);
    u16x4 h, l;
    h.x=f2b(v.x); h.y=f2b(v.y); h.z=f2b(v.z); h.w=f2b(v.w);
    l.x=f2b(v.x-b2f(h.x)); l.y=f2b(v.y-b2f(h.y)); l.z=f2b(v.z-b2f(h.z)); l.w=f2b(v.w-b2f(h.w));
    *(u16x4*)(hi + (size_t)i*4) = h;
    *(u16x4*)(lo + (size_t)i*4) = l;
  }
}
__global__ void pad_cvt(const float* __restrict__ s, u16* __restrict__ d,
                        int sr, int sc, int dr, int dc){
  int i = blockIdx.x*256 + threadIdx.x;
  if (i < dr*dc) {
    int r = i/dc, c = i%dc;
    float v = (r<sr && c<sc) ? s[(size_t)r*sc+c] : 0.f;
    d[i] = f2b(v);
  }
}
__global__ void pad_f32(const float* __restrict__ s, float* __restrict__ d, int sn, int dn){
  int i = blockIdx.x*256 + threadIdx.x;
  if (i < dn) d[i] = (i < sn) ? s[i] : 0.f;
}

// ---------------- row RMS (D=1024): invr[m] = 1/sqrt(mean(x^2)+eps) --------
__global__ __launch_bounds__(256) void row_rms(const float* __restrict__ x, float* __restrict__ invr){
  int m = blockIdx.x, tid = threadIdx.x;
  f32x4 v = *(const f32x4*)(x + (size_t)m*DD + tid*4);
  float s = v.x*v.x + v.y*v.y + v.z*v.z + v.w*v.w;
#pragma unroll
  for (int msk=1; msk<64; msk<<=1) s += __shfl_xor(s, msk);
  __shared__ float ws[4];
  if ((tid&63)==0) ws[tid>>6] = s;
  __syncthreads();
  if (tid==0) invr[m] = 1.f / sqrtf((ws[0]+ws[1]+ws[2]+ws[3])*(1.f/DD) + 1e-6f);
}

// ---------------- norm + causal depthwise conv + silu -> bf16 hi/lo --------
__global__ __launch_bounds__(256) void conv_silu_k(
    const float* __restrict__ x, const float* __restrict__ invr,
    const float* __restrict__ nw, const float* __restrict__ cw, const float* __restrict__ cb,
    u16* __restrict__ hbf, u16* __restrict__ hlo)
{
  int m = blockIdx.x, tid = threadIdx.x;
  int b = m >> 10, t = m & 1023;
  int d4 = tid * 4;
  f32x4 acc = *(const f32x4*)(cb + d4);
  f32x4 nwv = *(const f32x4*)(nw + d4);
  f32x4 w0 = *(const f32x4*)(cw + (size_t)(d4+0)*4);
  f32x4 w1 = *(const f32x4*)(cw + (size_t)(d4+1)*4);
  f32x4 w2 = *(const f32x4*)(cw + (size_t)(d4+2)*4);
  f32x4 w3 = *(const f32x4*)(cw + (size_t)(d4+3)*4);
#pragma unroll
  for (int j=0;j<4;j++) {
    int tt = t - 3 + j;
    if (tt >= 0) {
      int m2 = (b<<10) + tt;
      f32x4 xv = *(const f32x4*)(x + (size_t)m2*DD + d4);
      float sc = invr[m2];
      acc.x += xv.x * sc * nwv.x * w0[j];
      acc.y += xv.y * sc * nwv.y * w1[j];
      acc.z += xv.z * sc * nwv.z * w2[j];
      acc.w += xv.w * sc * nwv.w * w3[j];
    }
  }
  float h0 = silu_f(acc.x), h1 = silu_f(acc.y), h2 = silu_f(acc.z), h3 = silu_f(acc.w);
  size_t o = (size_t)m*DD + d4;
  u16x4 hv; hv.x=f2b(h0); hv.y=f2b(h1); hv.z=f2b(h2); hv.w=f2b(h3);
  u16x4 lv; lv.x=f2b(h0-b2f(hv.x)); lv.y=f2b(h1-b2f(hv.y)); lv.z=f2b(h2-b2f(hv.z)); lv.w=f2b(h3-b2f(hv.w));
  *(u16x4*)(hbf + o) = hv;
  *(u16x4*)(hlo + o) = lv;
}

// ---------------- q/k L2 normalization, per (m,h), one wave each -----------
__global__ __launch_bounds__(256) void qk_norm(float* __restrict__ q, float* __restrict__ k){
  int gw = blockIdx.x*4 + (threadIdx.x>>6);
  int lane = threadIdx.x & 63;
  size_t off = (size_t)(gw>>3)*DD + (size_t)(gw&7)*DKK;
  float q1 = q[off+lane], q2 = q[off+lane+64];
  float k1 = k[off+lane], k2 = k[off+lane+64];
  float sq = q1*q1+q2*q2, sk = k1*k1+k2*k2;
#pragma unroll
  for (int msk=1; msk<64; msk<<=1){ sq += __shfl_xor(sq,msk); sk += __shfl_xor(sk,msk); }
  float iq = 1.f/(sqrtf(sq)+1e-6f), ik = 1.f/(sqrtf(sk)+1e-6f);
  q[off+lane]=q1*iq; q[off+lane+64]=q2*iq;
  k[off+lane]=k1*ik; k[off+lane+64]=k2*ik;
}

// ---------------- headwise RMSNorm -> bf16 ---------------------------------
__global__ __launch_bounds__(256) void head_norm_k(
    const float* __restrict__ y, const float* __restrict__ w, u16* __restrict__ o)
{
  int gw = blockIdx.x*4 + (threadIdx.x>>6);
  int lane = threadIdx.x & 63;
  int h = gw & 7;
  size_t off = (size_t)(gw>>3)*DD + (size_t)h*DVV;
  float y1 = y[off+lane], y2 = y[off+lane+64];
  float s = y1*y1 + y2*y2;
#pragma unroll
  for (int msk=1; msk<64; msk<<=1) s += __shfl_xor(s,msk);
  float inv = 1.f / sqrtf(s*(1.f/DVV) + 1e-6f);
  o[off+lane]    = f2b(y1*inv*w[h*DVV+lane]);
  o[off+lane+64] = f2b(y2*inv*w[h*DVV+lane+64]);
}

// ---------------- fused LIF + gated delta-rule scan, state in registers ----
// grid = B*H*8 (dv split by 8 -> 256 blocks, 1 per CU), block 256:
// dkl = tid&15 (16 lanes x 8 dk each = one DPP row = full DK), dvl = tid>>4.
// LIF mem recurrence computed redundantly per row (VALU is idle anyway).
// Ring-4 register prefetch enforced with sched_barrier(0) so LLVM cannot
// sink the loads to their use sites (R3: VGPR=68 proved it did exactly that).
__global__ __launch_bounds__(256, 1) void scan_k(
    const float* __restrict__ q, const float* __restrict__ k, const float* __restrict__ v,
    const float* __restrict__ ab, const float* __restrict__ db, const float* __restrict__ bbase,
    const float* __restrict__ aspk, const float* __restrict__ bspk,
    const float* __restrict__ mem0, const float* __restrict__ s0p,
    float* __restrict__ y)
{
  const int bx = blockIdx.x;
  const int bh = bx >> 3, dvb = bx & 7;
  const int b = bh >> 3, h = bh & 7;
  const int tid = threadIdx.x;
  const int dvl = tid >> 4, dkl = tid & 15;
  const int dv = dvb*16 + dvl;
  const int dk0 = dkl*8;

  float s[8], mem[8], as8[8], bs8[8];
  {
    const float* sp = s0p + ((size_t)bh*DKK + dk0) * DVV + dv;
#pragma unroll
    for (int i=0;i<8;i++) s[i] = sp[(size_t)i*DVV];
#pragma unroll
    for (int i=0;i<8;i++) mem[i] = mem0[(size_t)bh*DKK + dk0 + i];
#pragma unroll
    for (int i=0;i<8;i++) as8[i] = aspk[h*DKK + dk0 + i];
#pragma unroll
    for (int i=0;i<8;i++) bs8[i] = bspk[h*DKK + dk0 + i];
  }
  const size_t rbase = ((size_t)b*TT)*DD + (size_t)h*DKK;
  const float* kP = k  + rbase + dk0;
  const float* qP = q  + rbase + dk0;
  const float* aP = ab + rbase + dk0;
  const float* dP = db + rbase + dk0;
  const float* vP = v  + rbase + dv;
  const float* bP = bbase + (size_t)b*TT*128 + h;
  float* yP = y + rbase + dv;

  struct Buf { f32x4 kk[2], qq[2], aa[2], dd[2]; float vv, bv; };
  Buf B0,B1,B2,B3;
  auto LOAD = [&](int t_, Buf& Bx){
    size_t o = (size_t)t_*DD;
    Bx.kk[0] = *(const f32x4*)(kP + o); Bx.kk[1] = *(const f32x4*)(kP + o + 4);
    Bx.qq[0] = *(const f32x4*)(qP + o); Bx.qq[1] = *(const f32x4*)(qP + o + 4);
    Bx.aa[0] = *(const f32x4*)(aP + o); Bx.aa[1] = *(const f32x4*)(aP + o + 4);
    Bx.dd[0] = *(const f32x4*)(dP + o); Bx.dd[1] = *(const f32x4*)(dP + o + 4);
    Bx.vv = vP[o];
    Bx.bv = bP[(size_t)t_*128];
  };
  auto STEP = [&](const Buf& Bx, int t_){
    // LIF: mem recurrence + spike (identical fp32 op sequence to reference)
    float cnt = 0.f, ss = 0.f, pp = 0.f;
    float sp[8];
#pragma unroll
    for (int i=0;i<2;i++)
#pragma unroll
      for (int e=0;e<4;e++){
        const int idx = i*4+e;
        float mv = 0.9f*mem[idx] + Bx.dd[i][e];
        float spv = mv > 0.5f ? 1.f : 0.f;
        mem[idx] = mv - spv*0.5f;
        sp[idx] = spv;
        cnt += spv;
        ss  += spv * bs8[idx];
      }
    // alpha = sigmoid(a_base + a_sp*spike); s *= alpha; pp += s*k
#pragma unroll
    for (int i=0;i<2;i++)
#pragma unroll
      for (int e=0;e<4;e++){
        const int idx = i*4+e;
        float av = sigm(Bx.aa[i][e] + as8[idx]*sp[idx]);
        float sv = s[idx] * av;
        s[idx] = sv;
        pp += sv * Bx.kk[i][e];
      }
    pp  = red16(pp);
    cnt = red16(cnt);
    ss  = red16(ss);
    float beta = (cnt > 0.f) ? sigm(Bx.bv + ss) : 0.f;
    float err = beta * (Bx.vv - pp);
    float oo = 0.f;
#pragma unroll
    for (int i=0;i<2;i++)
#pragma unroll
      for (int e=0;e<4;e++){
        const int idx = i*4+e;
        float sv = s[idx] + Bx.kk[i][e] * err;
        s[idx] = sv;
        oo += sv * Bx.qq[i][e];
      }
    oo = red16(oo);                 // output only: off the recurrence chain
    if (dkl == 0) yP[(size_t)t_*DD] = oo;
  };

#define SB __builtin_amdgcn_sched_barrier(0)
  LOAD(0, B0); LOAD(1, B1); LOAD(2, B2);
  SB;
  for (int t=0; t<TT; t+=4){
    LOAD(t+3 < TT ? t+3 : TT-1, B3); SB; STEP(B0, t);   SB;
    LOAD(t+4 < TT ? t+4 : TT-1, B0); SB; STEP(B1, t+1); SB;
    LOAD(t+5 < TT ? t+5 : TT-1, B1); SB; STEP(B2, t+2); SB;
    LOAD(t+6 < TT ? t+6 : TT-1, B2); SB; STEP(B3, t+3); SB;
  }
#undef SB
}

// ---------------- y1 = x + proj*sigmoid(gate_pre) --------------------------
__global__ __launch_bounds__(256) void gate_comb(
    const float* __restrict__ x, const float* __restrict__ p,
    const float* __restrict__ g, float* __restrict__ y1)
{
  size_t i = ((size_t)blockIdx.x*256 + threadIdx.x)*4;
  f32x4 xv = *(const f32x4*)(x+i);
  f32x4 pv = *(const f32x4*)(p+i);
  f32x4 gv = *(const f32x4*)(g+i);
  f32x4 o;
  o.x = xv.x + pv.x * sigm(gv.x);
  o.y = xv.y + pv.y * sigm(gv.y);
  o.z = xv.z + pv.z * sigm(gv.z);
  o.w = xv.w + pv.w * sigm(gv.w);
  *(f32x4*)(y1+i) = o;
}

// ---------------- z = bf16(y1 * invr * ff_norm_w) --------------------------
__global__ __launch_bounds__(256) void zscale(
    const float* __restrict__ y1, const float* __restrict__ invr,
    const float* __restrict__ w, u16* __restrict__ z)
{
  int m = blockIdx.x; int d4 = threadIdx.x*4;
  float sc = invr[m];
  f32x4 v = *(const f32x4*)(y1 + (size_t)m*DD + d4);
  f32x4 wv = *(const f32x4*)(w + d4);
  u16x4 o; o.x=f2b(v.x*sc*wv.x); o.y=f2b(v.y*sc*wv.y); o.z=f2b(v.z*sc*wv.z); o.w=f2b(v.w*sc*wv.w);
  *(u16x4*)(z + (size_t)m*DD + d4) = o;
}

extern "C" void kernel_launch(void* const* d_in, const int* in_sizes, int n_in,
                              void* d_out, int out_size, void* d_ws, size_t ws_size,
                              hipStream_t stream)
{
  (void)in_sizes; (void)n_in; (void)out_size; (void)ws_size;
  const float* x    = (const float*)d_in[0];
  const float* st0  = (const float*)d_in[1];
  const float* mem0 = (const float*)d_in[2];
  const float* nin  = (const float*)d_in[3];
  const float* cw   = (const float*)d_in[4];
  const float* cb   = (const float*)d_in[5];
  const float* qw   = (const float*)d_in[6];
  const float* kw   = (const float*)d_in[7];
  const float* vw   = (const float*)d_in[8];
  const float* ow   = (const float*)d_in[9];
  const float* sw   = (const float*)d_in[10];
  const float* aupw = (const float*)d_in[11];
  const float* aupb = (const float*)d_in[12];
  const float* adnw = (const float*)d_in[13];
  const float* adnb = (const float*)d_in[14];
  const float* aspk = (const float*)d_in[15];
  const float* betw = (const float*)d_in[16];
  const float* betb = (const float*)d_in[17];
  const float* bspk = (const float*)d_in[18];
  const float* hnw  = (const float*)d_in[19];
  const float* u1w  = (const float*)d_in[20];
  const float* u1b  = (const float*)d_in[21];
  const float* u2w  = (const float*)d_in[22];
  const float* u2b  = (const float*)d_in[23];
  const float* ffnw = (const float*)d_in[24];
  const float* fw1  = (const float*)d_in[25];
  const float* fw3  = (const float*)d_in[26];
  const float* fw2  = (const float*)d_in[27];
  float* out = (float*)d_out;

  char* wsb = (char*)d_ws;
  size_t off = 0;
  auto alloc = [&](size_t bytes)->char*{
    off = (off + 255) & ~(size_t)255;
    char* p = wsb + off; off += bytes; return p;
  };

  // persistent
  u16* qwb  = (u16*)alloc((size_t)DD*DD*2);
  u16* kwb  = (u16*)alloc((size_t)DD*DD*2);
  u16* vwb  = (u16*)alloc((size_t)DD*DD*2);
  u16* owb  = (u16*)alloc((size_t)DD*DD*2);
  u16* swhi = (u16*)alloc((size_t)DD*DD*2);
  u16* swlo = (u16*)alloc((size_t)DD*DD*2);
  u16* fw1b = (u16*)alloc((size_t)DFF*DD*2);
  u16* fw3b = (u16*)alloc((size_t)DFF*DD*2);
  u16* fw2b = (u16*)alloc((size_t)DD*DFF*2);
  u16* aupwb= (u16*)alloc((size_t)128*DD*2);
  u16* adnwb= (u16*)alloc((size_t)DD*128*2);
  u16* betwb= (u16*)alloc((size_t)128*DD*2);
  u16* u1wb = (u16*)alloc((size_t)128*DD*2);
  u16* u2wb = (u16*)alloc((size_t)DD*128*2);
  float* aupbp = (float*)alloc(128*4);
  float* betbp = (float*)alloc(128*4);
  float* u1bp  = (float*)alloc(128*4);
  u16* xbf  = (u16*)alloc((size_t)MM*DD*2);
  float* yatt  = (float*)alloc((size_t)MM*DD*4);
  u16* yattb = (u16*)alloc((size_t)MM*DD*2);
  float* invr  = (float*)alloc((size_t)MM*4);

  // early region
  size_t mark = off;
  u16* hbf = (u16*)alloc((size_t)MM*DD*2);
  u16* hlo = (u16*)alloc((size_t)MM*DD*2);
  float* qb = (float*)alloc((size_t)MM*DD*4);
  float* kb = (float*)alloc((size_t)MM*DD*4);
  float* vb = (float*)alloc((size_t)MM*DD*4);
  float* db = (float*)alloc((size_t)MM*DD*4);
  float* abase = (float*)alloc((size_t)MM*DD*4);
  float* bbase = (float*)alloc((size_t)MM*128*4);
  u16* gsm  = (u16*)alloc((size_t)MM*128*2);
  // late region (aliases early; early all dead by then)
  off = mark;
  float* proj = (float*)alloc((size_t)MM*DD*4);
  float* gpre = (float*)alloc((size_t)MM*DD*4);
  u16* zbf  = (u16*)alloc((size_t)MM*DD*2);
  u16* g1   = (u16*)alloc((size_t)MM*128*2);
  float* ffa  = (float*)alloc((size_t)1024*DFF*4);
  u16* ffh  = (u16*)alloc((size_t)MM*DFF*2);

  dim3 blk(256);
  auto CVT = [&](const float* s, u16* d, int n){
    cvt_bf16<<<dim3((n/4+255)/256), blk, 0, stream>>>(s, d, n);
  };
  CVT(qw, qwb, DD*DD); CVT(kw, kwb, DD*DD); CVT(vw, vwb, DD*DD); CVT(ow, owb, DD*DD);
  CVT(fw1, fw1b, DFF*DD); CVT(fw3, fw3b, DFF*DD); CVT(fw2, fw2b, DD*DFF);
  CVT(x, xbf, MM*DD);
  cvt_split<<<dim3((DD*DD/4+255)/256), blk, 0, stream>>>(sw, swhi, swlo, DD*DD);
  pad_cvt<<<dim3((128*DD+255)/256), blk, 0, stream>>>(aupw, aupwb, 64, DD, 128, DD);
  pad_cvt<<<dim3((DD*128+255)/256), blk, 0, stream>>>(adnw, adnwb, DD, 64, DD, 128);
  pad_cvt<<<dim3((128*DD+255)/256), blk, 0, stream>>>(betw, betwb, 8, DD, 128, DD);
  pad_cvt<<<dim3((128*DD+255)/256), blk, 0, stream>>>(u1w, u1wb, 64, DD, 128, DD);
  pad_cvt<<<dim3((DD*128+255)/256), blk, 0, stream>>>(u2w, u2wb, DD, 64, DD, 128);
  pad_f32<<<dim3(1), blk, 0, stream>>>(aupb, aupbp, 64, 128);
  pad_f32<<<dim3(1), blk, 0, stream>>>(betb, betbp, 8, 128);
  pad_f32<<<dim3(1), blk, 0, stream>>>(u1b, u1bp, 64, 128);

  // norm + conv + silu
  row_rms<<<dim3(MM), blk, 0, stream>>>(x, invr);
  conv_silu_k<<<dim3(MM), blk, 0, stream>>>(x, invr, nin, cw, cb, hbf, hlo);

  dim3 gMN(MM/128, DD/128);
  dim3 gM128(MM/128, 1);
  // q, k, v
  gemm_bt<0><<<gMN, blk, 0, stream>>>(hbf, qwb, qb, nullptr, nullptr, nullptr, MM, DD, DD);
  gemm_bt<0><<<gMN, blk, 0, stream>>>(hbf, kwb, kb, nullptr, nullptr, nullptr, MM, DD, DD);
  gemm_bt<0><<<gMN, blk, 0, stream>>>(hbf, vwb, vb, nullptr, nullptr, nullptr, MM, DD, DD);
  // drive in split-bf16 (3 passes) for spike-threshold accuracy
  gemm_bt<0><<<gMN, blk, 0, stream>>>(hbf, swhi, db, nullptr, nullptr, nullptr, MM, DD, DD);
  gemm_bt<1><<<gMN, blk, 0, stream>>>(hbf, swlo, db, nullptr, nullptr, nullptr, MM, DD, DD);
  gemm_bt<1><<<gMN, blk, 0, stream>>>(hlo, swhi, db, nullptr, nullptr, nullptr, MM, DD, DD);
  // beta base [M,128] (cols 0..7 used)
  gemm_bt<0><<<gM128, blk, 0, stream>>>(hbf, betwb, bbase, nullptr, betbp, nullptr, MM, 128, DD);
  // alpha base: silu(h@up+b) @ down + b
  gemm_bt<2><<<gM128, blk, 0, stream>>>(hbf, aupwb, nullptr, gsm, aupbp, nullptr, MM, 128, DD);
  gemm_bt<0><<<gMN, blk, 0, stream>>>(gsm, adnwb, abase, nullptr, adnb, nullptr, MM, DD, 128);

  qk_norm<<<dim3(MM*HH/4), blk, 0, stream>>>(qb, kb);
  scan_k<<<dim3(BB*HH*8), blk, 0, stream>>>(qb, kb, vb, abase, db, bbase,
                                            aspk, bspk, mem0, st0, yatt);
  head_norm_k<<<dim3(MM*HH/4), blk, 0, stream>>>(yatt, hnw, yattb);

  // out proj, gate, combine
  gemm_bt<0><<<gMN, blk, 0, stream>>>(yattb, owb, proj, nullptr, nullptr, nullptr, MM, DD, DD);
  gemm_bt<2><<<gM128, blk, 0, stream>>>(xbf, u1wb, nullptr, g1, u1bp, nullptr, MM, 128, DD);
  gemm_bt<0><<<gMN, blk, 0, stream>>>(g1, u2wb, gpre, nullptr, u2b, nullptr, MM, DD, 128);
  gate_comb<<<dim3(MM*DD/1024), blk, 0, stream>>>(x, proj, gpre, out);

  // FFN
  row_rms<<<dim3(MM), blk, 0, stream>>>(out, invr);
  zscale<<<dim3(MM), blk, 0, stream>>>(out, invr, ffnw, zbf);
  for (int c=0; c<4; ++c) {
    const u16* zc = zbf + (size_t)c*1024*DD;
    dim3 gC(1024/128, DFF/128);
    gemm_bt<0><<<gC, blk, 0, stream>>>(zc, fw1b, ffa, nullptr, nullptr, nullptr, 1024, DFF, DD);
    gemm_bt<3><<<gC, blk, 0, stream>>>(zc, fw3b, nullptr, ffh + (size_t)c*1024*DFF, nullptr, ffa, 1024, DFF, DD);
  }
  gemm_bt<1><<<gMN, blk, 0, stream>>>(ffh, fw2b, out, nullptr, nullptr, nullptr, MM, DD, DFF);
}

// Round 5
// 1157.312 us; speedup vs baseline: 1.0891x; 1.0891x over previous
//
#include <hip/hip_runtime.h>
#include <hip/hip_bf16.h>
#include <stdint.h>

#define DEV static __device__ __forceinline__

typedef float f32x4 __attribute__((ext_vector_type(4)));
typedef short bf16x8 __attribute__((ext_vector_type(8)));
typedef float accf4 __attribute__((ext_vector_type(4)));
typedef unsigned short u16;
typedef unsigned int u32;
typedef u16 u16x4 __attribute__((ext_vector_type(4)));

#define BB 4
#define TT 1024
#define DD 1024
#define HH 8
#define DKK 128
#define DVV 128
#define MM (BB*TT)
#define DFF 4096

DEV u16 f2b(float f){
  union { float f; u32 u; } v; v.f = f;
  u32 r = (v.u + 0x7fffu + ((v.u >> 16) & 1u)) >> 16;
  return (u16)r;
}
DEV float b2f(u16 h){
  union { u32 u; float f; } v; v.u = ((u32)h) << 16;
  return v.f;
}
DEV float sigm(float x){ return 1.f / (1.f + __expf(-x)); }
DEV float silu_f(float x){ return x / (1.f + __expf(-x)); }

DEV void gl_lds16(const void* g, void* l){
  __builtin_amdgcn_global_load_lds(
      (const __attribute__((address_space(1))) void*)g,
      (__attribute__((address_space(3))) void*)l, 16, 0, 0);
}

// ---- DPP cross-lane adds (VALU pipe, ~4cy latency each; no LDS traffic) ----
template<int CTRL>
DEV float dpp_add(float x){
  union { float f; int i; } u; u.f = x;
  int y = __builtin_amdgcn_update_dpp(0, u.i, CTRL, 0xf, 0xf, true);
  union { int i; float f; } w; w.i = y;
  return x + w.f;
}
// sum over 16-lane DPP row; all 16 lanes end with the full sum
DEV float red16(float x){
  x = dpp_add<0xB1>(x);  // quad_perm [1,0,3,2]  (xor 1)
  x = dpp_add<0x4E>(x);  // quad_perm [2,3,0,1]  (xor 2)
  x = dpp_add<0x141>(x); // row_half_mirror      (pairs 4-groups)
  x = dpp_add<0x140>(x); // row_mirror           (pairs 8-groups)
  return x;
}
// sum over full wave64; lane 63 ends with the full sum
DEV float red64_last(float x){
  x = red16(x);
  x = dpp_add<0x142>(x); // row_bcast15
  x = dpp_add<0x143>(x); // row_bcast31
  return x;
}

// ---------------- GEMM: C[M,N] = A[M,K](bf16) * B[N,K](bf16)^T ---------------
// OP 0: C=acc(+bias)   OP 1: C+=acc   OP 2: Cb=bf16(silu(acc+bias))
// OP 3: Cb=bf16(silu(aux)*acc)
template<int OP>
__global__ __launch_bounds__(256) void gemm_bt(
    const u16* __restrict__ A, const u16* __restrict__ Bm,
    float* __restrict__ C, u16* __restrict__ Cb,
    const float* __restrict__ bias, const float* __restrict__ aux,
    int M, int N, int K)
{
  __shared__ u16 lsA[128*64];
  __shared__ u16 lsB[128*64];
  const int tid = threadIdx.x;
  const int bm = blockIdx.x, bn = blockIdx.y;
  const int wid = tid >> 6, lane = tid & 63;
  const int wr = wid >> 1, wc = wid & 1;
  const int fr = lane & 15, fq = lane >> 4;
  accf4 acc[4][4];
#pragma unroll
  for (int i=0;i<4;i++)
#pragma unroll
    for (int j=0;j<4;j++) acc[i][j] = (accf4)0.f;

  const int srow = tid >> 3;
  const int sk = (tid & 7) * 8;
  const u16* aP = A + (size_t)(bm*128 + srow) * K + sk;
  const u16* bP = Bm + (size_t)(bn*128 + srow) * K + sk;
  char* lA = (char*)lsA + tid*16;
  char* lB = (char*)lsB + tid*16;

  for (int kt = 0; kt < K; kt += 64) {
#pragma unroll
    for (int it=0; it<4; ++it) {
      gl_lds16(aP + (size_t)it*32*K + kt, lA + it*4096);
      gl_lds16(bP + (size_t)it*32*K + kt, lB + it*4096);
    }
    asm volatile("s_waitcnt vmcnt(0)" ::: "memory");
    __syncthreads();
#pragma unroll
    for (int ks=0; ks<2; ++ks) {
      bf16x8 av[4], bv[4];
#pragma unroll
      for (int i=0;i<4;i++)
        av[i] = *(const bf16x8*)&lsA[(wr*64 + i*16 + fr)*64 + ks*32 + fq*8];
#pragma unroll
      for (int j=0;j<4;j++)
        bv[j] = *(const bf16x8*)&lsB[(wc*64 + j*16 + fr)*64 + ks*32 + fq*8];
#pragma unroll
      for (int i=0;i<4;i++)
#pragma unroll
        for (int j=0;j<4;j++)
          acc[i][j] = __builtin_amdgcn_mfma_f32_16x16x32_bf16(av[i], bv[j], acc[i][j], 0, 0, 0);
    }
    __syncthreads();
  }

#pragma unroll
  for (int i=0;i<4;i++) {
    const int r0 = bm*128 + wr*64 + i*16 + fq*4;
#pragma unroll
    for (int j=0;j<4;j++) {
      const int c = bn*128 + wc*64 + j*16 + fr;
#pragma unroll
      for (int rr=0; rr<4; ++rr) {
        const size_t idx = (size_t)(r0+rr)*N + c;
        float v = acc[i][j][rr];
        if (OP == 0) { if (bias) v += bias[c]; C[idx] = v; }
        if (OP == 1) { C[idx] += v; }
        if (OP == 2) { v += bias[c]; Cb[idx] = f2b(silu_f(v)); }
        if (OP == 3) { Cb[idx] = f2b(silu_f(aux[idx]) * v); }
      }
    }
  }
}

// ---------------- conversions ----------------
__global__ void cvt_bf16(const float* __restrict__ s, u16* __restrict__ d, int n){
  int i = blockIdx.x*256 + threadIdx.x;
  if (i*4 < n) {
    f32x4 v = *(const f32x4*)(s + (size_t)i*4);
    u16x4 o; o.x=f2b(v.x); o.y=f2b(v.y); o.z=f2b(v.z); o.w=f2b(v.w);
    *(u16x4*)(d + (size_t)i*4) = o;
  }
}
__global__ void cvt_split(const float* __restrict__ s, u16* __restrict__ hi, u16* __restrict__ lo, int n){
  int i = blockIdx.x*256 + threadIdx.x;
  if (i*4 < n) {
    f32x4 v = *(const f32x4*)(s + (size_t)i*4);
    u16x4 h, l;
    h.x=f2b(v.x); h.y=f2b(v.y); h.z=f2b(v.z); h.w=f2b(v.w);
    l.x=f2b(v.x-b2f(h.x)); l.y=f2b(v.y-b2f(h.y)); l.z=f2b(v.z-b2f(h.z)); l.w=f2b(v.w-b2f(h.w));
    *(u16x4*)(hi + (size_t)i*4) = h;
    *(u16x4*)(lo + (size_t)i*4) = l;
  }
}
__global__ void pad_cvt(const float* __restrict__ s, u16* __restrict__ d,
                        int sr, int sc, int dr, int dc){
  int i = blockIdx.x*256 + threadIdx.x;
  if (i < dr*dc) {
    int r = i/dc, c = i%dc;
    float v = (r<sr && c<sc) ? s[(size_t)r*sc+c] : 0.f;
    d[i] = f2b(v);
  }
}
__global__ void pad_f32(const float* __restrict__ s, float* __restrict__ d, int sn, int dn){
  int i = blockIdx.x*256 + threadIdx.x;
  if (i < dn) d[i] = (i < sn) ? s[i] : 0.f;
}

// ---------------- row RMS (D=1024): invr[m] = 1/sqrt(mean(x^2)+eps) --------
__global__ __launch_bounds__(256) void row_rms(const float* __restrict__ x, float* __restrict__ invr){
  int m = blockIdx.x, tid = threadIdx.x;
  f32x4 v = *(const f32x4*)(x + (size_t)m*DD + tid*4);
  float s = v.x*v.x + v.y*v.y + v.z*v.z + v.w*v.w;
#pragma unroll
  for (int msk=1; msk<64; msk<<=1) s += __shfl_xor(s, msk);
  __shared__ float ws[4];
  if ((tid&63)==0) ws[tid>>6] = s;
  __syncthreads();
  if (tid==0) invr[m] = 1.f / sqrtf((ws[0]+ws[1]+ws[2]+ws[3])*(1.f/DD) + 1e-6f);
}

// ---------------- norm + causal depthwise conv + silu -> bf16 hi/lo --------
__global__ __launch_bounds__(256) void conv_silu_k(
    const float* __restrict__ x, const float* __restrict__ invr,
    const float* __restrict__ nw, const float* __restrict__ cw, const float* __restrict__ cb,
    u16* __restrict__ hbf, u16* __restrict__ hlo)
{
  int m = blockIdx.x, tid = threadIdx.x;
  int b = m >> 10, t = m & 1023;
  int d4 = tid * 4;
  f32x4 acc = *(const f32x4*)(cb + d4);
  f32x4 nwv = *(const f32x4*)(nw + d4);
  f32x4 w0 = *(const f32x4*)(cw + (size_t)(d4+0)*4);
  f32x4 w1 = *(const f32x4*)(cw + (size_t)(d4+1)*4);
  f32x4 w2 = *(const f32x4*)(cw + (size_t)(d4+2)*4);
  f32x4 w3 = *(const f32x4*)(cw + (size_t)(d4+3)*4);
#pragma unroll
  for (int j=0;j<4;j++) {
    int tt = t - 3 + j;
    if (tt >= 0) {
      int m2 = (b<<10) + tt;
      f32x4 xv = *(const f32x4*)(x + (size_t)m2*DD + d4);
      float sc = invr[m2];
      acc.x += xv.x * sc * nwv.x * w0[j];
      acc.y += xv.y * sc * nwv.y * w1[j];
      acc.z += xv.z * sc * nwv.z * w2[j];
      acc.w += xv.w * sc * nwv.w * w3[j];
    }
  }
  float h0 = silu_f(acc.x), h1 = silu_f(acc.y), h2 = silu_f(acc.z), h3 = silu_f(acc.w);
  size_t o = (size_t)m*DD + d4;
  u16x4 hv; hv.x=f2b(h0); hv.y=f2b(h1); hv.z=f2b(h2); hv.w=f2b(h3);
  u16x4 lv; lv.x=f2b(h0-b2f(hv.x)); lv.y=f2b(h1-b2f(hv.y)); lv.z=f2b(h2-b2f(hv.z)); lv.w=f2b(h3-b2f(hv.w));
  *(u16x4*)(hbf + o) = hv;
  *(u16x4*)(hlo + o) = lv;
}

// ---------------- q/k L2 normalization, per (m,h), one wave each -----------
__global__ __launch_bounds__(256) void qk_norm(float* __restrict__ q, float* __restrict__ k){
  int gw = blockIdx.x*4 + (threadIdx.x>>6);
  int lane = threadIdx.x & 63;
  size_t off = (size_t)(gw>>3)*DD + (size_t)(gw&7)*DKK;
  float q1 = q[off+lane], q2 = q[off+lane+64];
  float k1 = k[off+lane], k2 = k[off+lane+64];
  float sq = q1*q1+q2*q2, sk = k1*k1+k2*k2;
#pragma unroll
  for (int msk=1; msk<64; msk<<=1){ sq += __shfl_xor(sq,msk); sk += __shfl_xor(sk,msk); }
  float iq = 1.f/(sqrtf(sq)+1e-6f), ik = 1.f/(sqrtf(sk)+1e-6f);
  q[off+lane]=q1*iq; q[off+lane+64]=q2*iq;
  k[off+lane]=k1*ik; k[off+lane+64]=k2*ik;
}

// ---------------- headwise RMSNorm -> bf16 ---------------------------------
__global__ __launch_bounds__(256) void head_norm_k(
    const float* __restrict__ y, const float* __restrict__ w, u16* __restrict__ o)
{
  int gw = blockIdx.x*4 + (threadIdx.x>>6);
  int lane = threadIdx.x & 63;
  int h = gw & 7;
  size_t off = (size_t)(gw>>3)*DD + (size_t)h*DVV;
  float y1 = y[off+lane], y2 = y[off+lane+64];
  float s = y1*y1 + y2*y2;
#pragma unroll
  for (int msk=1; msk<64; msk<<=1) s += __shfl_xor(s,msk);
  float inv = 1.f / sqrtf(s*(1.f/DVV) + 1e-6f);
  o[off+lane]    = f2b(y1*inv*w[h*DVV+lane]);
  o[off+lane+64] = f2b(y2*inv*w[h*DVV+lane+64]);
}

// ---------------- LIF spike precompute: alpha (in-place), bscale -----------
// One wave per (b,h). Ring-8 register prefetch enforced by sched_barrier(0)
// (R4 proved SB keeps the ring; R3's 248us was the collapsed-prefetch cost).
// Applies the sigmoids HERE so scan_k's recurrence has no transcendentals.
__global__ __launch_bounds__(64) void spike_prep(
    const float* __restrict__ dr, const float* ab, const float* __restrict__ bb,
    const float* __restrict__ aspk, const float* __restrict__ bspk,
    const float* __restrict__ mem0, float* al, float* __restrict__ bs)
{
  const int bh = blockIdx.x, b = bh>>3, h = bh&7;
  const int lane = threadIdx.x;
  float m1 = mem0[bh*DKK + lane], m2 = mem0[bh*DKK + lane + 64];
  const float a1s = aspk[h*DKK+lane], a2s = aspk[h*DKK+lane+64];
  const float b1s = bspk[h*DKK+lane], b2s = bspk[h*DKK+lane+64];
  const size_t rbase = ((size_t)b*TT)*DD + (size_t)h*DKK;
  const size_t bbase = (size_t)b*TT;

  struct SBf { float d1,d2,a1,a2,bv; };
  SBf r0,r1,r2,r3,r4,r5,r6,r7;
  auto LOADS = [&](int t_, SBf& S){
    size_t o = rbase + (size_t)t_*DD;
    S.d1 = dr[o+lane]; S.d2 = dr[o+lane+64];
    S.a1 = ab[o+lane]; S.a2 = ab[o+lane+64];
    S.bv = bb[(bbase + t_)*128 + h];
  };
  auto STEPS = [&](const SBf& S, int t_){
    m1 = 0.9f*m1 + S.d1; m2 = 0.9f*m2 + S.d2;
    float sp1 = m1 > 0.5f ? 1.f : 0.f;
    float sp2 = m2 > 0.5f ? 1.f : 0.f;
    m1 -= sp1*0.5f; m2 -= sp2*0.5f;
    float ss = red64_last(sp1*b1s + sp2*b2s);
    unsigned long long anyb = __ballot((sp1+sp2) > 0.f);
    size_t o = rbase + (size_t)t_*DD;
    al[o+lane]    = sigm(S.a1 + a1s*sp1);
    al[o+lane+64] = sigm(S.a2 + a2s*sp2);
    if (lane==63) bs[(bbase + t_)*HH + h] = (anyb != 0ull) ? sigm(S.bv + ss) : 0.f;
  };

#define SBAR __builtin_amdgcn_sched_barrier(0)
  LOADS(0,r0); LOADS(1,r1); LOADS(2,r2); LOADS(3,r3);
  LOADS(4,r4); LOADS(5,r5); LOADS(6,r6);
  SBAR;
  for (int t=0; t<TT; t+=8){
    LOADS(t+ 7 < TT ? t+ 7 : TT-1, r7); SBAR; STEPS(r0, t);   SBAR;
    LOADS(t+ 8 < TT ? t+ 8 : TT-1, r0); SBAR; STEPS(r1, t+1); SBAR;
    LOADS(t+ 9 < TT ? t+ 9 : TT-1, r1); SBAR; STEPS(r2, t+2); SBAR;
    LOADS(t+10 < TT ? t+10 : TT-1, r2); SBAR; STEPS(r3, t+3); SBAR;
    LOADS(t+11 < TT ? t+11 : TT-1, r3); SBAR; STEPS(r4, t+4); SBAR;
    LOADS(t+12 < TT ? t+12 : TT-1, r4); SBAR; STEPS(r5, t+5); SBAR;
    LOADS(t+13 < TT ? t+13 : TT-1, r5); SBAR; STEPS(r6, t+6); SBAR;
    LOADS(t+14 < TT ? t+14 : TT-1, r6); SBAR; STEPS(r7, t+7); SBAR;
  }
#undef SBAR
}

// ---------------- gated delta-rule scan, state in registers ----------------
// grid = B*H*8 (dv split by 8 -> 256 blocks, 1 per CU), block 256:
// dkl = tid&15 (16 lanes x 8 dk = one DPP row = full DK), dvl = tid>>4.
// Lean step (~50 VALU, no transcendentals); ring-8 prefetch (+~700cy
// lookahead) enforced by sched_barrier(0).
__global__ __launch_bounds__(256, 1) void scan_k(
    const float* __restrict__ q, const float* __restrict__ k, const float* __restrict__ v,
    const float* __restrict__ al, const float* __restrict__ bs,
    const float* __restrict__ s0p, float* __restrict__ y)
{
  const int bx = blockIdx.x;
  const int bh = bx >> 3, dvb = bx & 7;
  const int b = bh >> 3, h = bh & 7;
  const int tid = threadIdx.x;
  const int dvl = tid >> 4, dkl = tid & 15;
  const int dv = dvb*16 + dvl;
  const int dk0 = dkl*8;

  float s[8];
  {
    const float* sp = s0p + ((size_t)bh*DKK + dk0) * DVV + dv;
#pragma unroll
    for (int i=0;i<8;i++) s[i] = sp[(size_t)i*DVV];
  }
  const size_t rbase = ((size_t)b*TT)*DD + (size_t)h*DKK;
  const float* kP = k  + rbase + dk0;
  const float* qP = q  + rbase + dk0;
  const float* aP = al + rbase + dk0;
  const float* vP = v  + rbase + dv;
  const float* bP = bs + (size_t)b*TT*HH + h;
  float* yP = y + rbase + dv;

  struct Buf { f32x4 kk[2], qq[2], aa[2]; float vv, bb; };
  Buf B0,B1,B2,B3,B4,B5,B6,B7;
  auto LOAD = [&](int t_, Buf& Bx){
    size_t o = (size_t)t_*DD;
    Bx.kk[0] = *(const f32x4*)(kP + o); Bx.kk[1] = *(const f32x4*)(kP + o + 4);
    Bx.qq[0] = *(const f32x4*)(qP + o); Bx.qq[1] = *(const f32x4*)(qP + o + 4);
    Bx.aa[0] = *(const f32x4*)(aP + o); Bx.aa[1] = *(const f32x4*)(aP + o + 4);
    Bx.vv = vP[o];
    Bx.bb = bP[(size_t)t_*HH];
  };
  auto STEP = [&](const Buf& Bx, int t_){
    float pp = 0.f, pp2 = 0.f;
#pragma unroll
    for (int i=0;i<2;i++)
#pragma unroll
      for (int e=0;e<4;e++){
        float sv = s[i*4+e] * Bx.aa[i][e];
        s[i*4+e] = sv;
        if (e < 2) pp += sv * Bx.kk[i][e]; else pp2 += sv * Bx.kk[i][e];
      }
    pp = red16(pp + pp2);
    float err = Bx.bb * (Bx.vv - pp);
    float oo = 0.f, oo2 = 0.f;
#pragma unroll
    for (int i=0;i<2;i++)
#pragma unroll
      for (int e=0;e<4;e++){
        float sv = s[i*4+e] + Bx.kk[i][e] * err;
        s[i*4+e] = sv;
        if (e < 2) oo += sv * Bx.qq[i][e]; else oo2 += sv * Bx.qq[i][e];
      }
    oo = red16(oo + oo2);           // output only: off the recurrence chain
    if (dkl == 0) yP[(size_t)t_*DD] = oo;
  };

#define SBAR __builtin_amdgcn_sched_barrier(0)
  LOAD(0,B0); LOAD(1,B1); LOAD(2,B2); LOAD(3,B3);
  LOAD(4,B4); LOAD(5,B5); LOAD(6,B6);
  SBAR;
  for (int t=0; t<TT; t+=8){
    LOAD(t+ 7 < TT ? t+ 7 : TT-1, B7); SBAR; STEP(B0, t);   SBAR;
    LOAD(t+ 8 < TT ? t+ 8 : TT-1, B0); SBAR; STEP(B1, t+1); SBAR;
    LOAD(t+ 9 < TT ? t+ 9 : TT-1, B1); SBAR; STEP(B2, t+2); SBAR;
    LOAD(t+10 < TT ? t+10 : TT-1, B2); SBAR; STEP(B3, t+3); SBAR;
    LOAD(t+11 < TT ? t+11 : TT-1, B3); SBAR; STEP(B4, t+4); SBAR;
    LOAD(t+12 < TT ? t+12 : TT-1, B4); SBAR; STEP(B5, t+5); SBAR;
    LOAD(t+13 < TT ? t+13 : TT-1, B5); SBAR; STEP(B6, t+6); SBAR;
    LOAD(t+14 < TT ? t+14 : TT-1, B6); SBAR; STEP(B7, t+7); SBAR;
  }
#undef SBAR
}

// ---------------- y1 = x + proj*sigmoid(gate_pre) --------------------------
__global__ __launch_bounds__(256) void gate_comb(
    const float* __restrict__ x, const float* __restrict__ p,
    const float* __restrict__ g, float* __restrict__ y1)
{
  size_t i = ((size_t)blockIdx.x*256 + threadIdx.x)*4;
  f32x4 xv = *(const f32x4*)(x+i);
  f32x4 pv = *(const f32x4*)(p+i);
  f32x4 gv = *(const f32x4*)(g+i);
  f32x4 o;
  o.x = xv.x + pv.x * sigm(gv.x);
  o.y = xv.y + pv.y * sigm(gv.y);
  o.z = xv.z + pv.z * sigm(gv.z);
  o.w = xv.w + pv.w * sigm(gv.w);
  *(f32x4*)(y1+i) = o;
}

// ---------------- z = bf16(y1 * invr * ff_norm_w) --------------------------
__global__ __launch_bounds__(256) void zscale(
    const float* __restrict__ y1, const float* __restrict__ invr,
    const float* __restrict__ w, u16* __restrict__ z)
{
  int m = blockIdx.x; int d4 = threadIdx.x*4;
  float sc = invr[m];
  f32x4 v = *(const f32x4*)(y1 + (size_t)m*DD + d4);
  f32x4 wv = *(const f32x4*)(w + d4);
  u16x4 o; o.x=f2b(v.x*sc*wv.x); o.y=f2b(v.y*sc*wv.y); o.z=f2b(v.z*sc*wv.z); o.w=f2b(v.w*sc*wv.w);
  *(u16x4*)(z + (size_t)m*DD + d4) = o;
}

extern "C" void kernel_launch(void* const* d_in, const int* in_sizes, int n_in,
                              void* d_out, int out_size, void* d_ws, size_t ws_size,
                              hipStream_t stream)
{
  (void)in_sizes; (void)n_in; (void)out_size; (void)ws_size;
  const float* x    = (const float*)d_in[0];
  const float* st0  = (const float*)d_in[1];
  const float* mem0 = (const float*)d_in[2];
  const float* nin  = (const float*)d_in[3];
  const float* cw   = (const float*)d_in[4];
  const float* cb   = (const float*)d_in[5];
  const float* qw   = (const float*)d_in[6];
  const float* kw   = (const float*)d_in[7];
  const float* vw   = (const float*)d_in[8];
  const float* ow   = (const float*)d_in[9];
  const float* sw   = (const float*)d_in[10];
  const float* aupw = (const float*)d_in[11];
  const float* aupb = (const float*)d_in[12];
  const float* adnw = (const float*)d_in[13];
  const float* adnb = (const float*)d_in[14];
  const float* aspk = (const float*)d_in[15];
  const float* betw = (const float*)d_in[16];
  const float* betb = (const float*)d_in[17];
  const float* bspk = (const float*)d_in[18];
  const float* hnw  = (const float*)d_in[19];
  const float* u1w  = (const float*)d_in[20];
  const float* u1b  = (const float*)d_in[21];
  const float* u2w  = (const float*)d_in[22];
  const float* u2b  = (const float*)d_in[23];
  const float* ffnw = (const float*)d_in[24];
  const float* fw1  = (const float*)d_in[25];
  const float* fw3  = (const float*)d_in[26];
  const float* fw2  = (const float*)d_in[27];
  float* out = (float*)d_out;

  char* wsb = (char*)d_ws;
  size_t off = 0;
  auto alloc = [&](size_t bytes)->char*{
    off = (off + 255) & ~(size_t)255;
    char* p = wsb + off; off += bytes; return p;
  };

  // persistent
  u16* qwb  = (u16*)alloc((size_t)DD*DD*2);
  u16* kwb  = (u16*)alloc((size_t)DD*DD*2);
  u16* vwb  = (u16*)alloc((size_t)DD*DD*2);
  u16* owb  = (u16*)alloc((size_t)DD*DD*2);
  u16* swhi = (u16*)alloc((size_t)DD*DD*2);
  u16* swlo = (u16*)alloc((size_t)DD*DD*2);
  u16* fw1b = (u16*)alloc((size_t)DFF*DD*2);
  u16* fw3b = (u16*)alloc((size_t)DFF*DD*2);
  u16* fw2b = (u16*)alloc((size_t)DD*DFF*2);
  u16* aupwb= (u16*)alloc((size_t)128*DD*2);
  u16* adnwb= (u16*)alloc((size_t)DD*128*2);
  u16* betwb= (u16*)alloc((size_t)128*DD*2);
  u16* u1wb = (u16*)alloc((size_t)128*DD*2);
  u16* u2wb = (u16*)alloc((size_t)DD*128*2);
  float* aupbp = (float*)alloc(128*4);
  float* betbp = (float*)alloc(128*4);
  float* u1bp  = (float*)alloc(128*4);
  u16* xbf  = (u16*)alloc((size_t)MM*DD*2);
  float* yatt  = (float*)alloc((size_t)MM*DD*4);
  u16* yattb = (u16*)alloc((size_t)MM*DD*2);
  float* invr  = (float*)alloc((size_t)MM*4);

  // early region
  size_t mark = off;
  u16* hbf = (u16*)alloc((size_t)MM*DD*2);
  u16* hlo = (u16*)alloc((size_t)MM*DD*2);
  float* qb = (float*)alloc((size_t)MM*DD*4);
  float* kb = (float*)alloc((size_t)MM*DD*4);
  float* vb = (float*)alloc((size_t)MM*DD*4);
  float* db = (float*)alloc((size_t)MM*DD*4);
  float* abase = (float*)alloc((size_t)MM*DD*4);   // becomes alpha in place
  float* bbase = (float*)alloc((size_t)MM*128*4);
  float* bscale= (float*)alloc((size_t)MM*8*4);
  u16* gsm  = (u16*)alloc((size_t)MM*128*2);
  // late region (aliases early; early all dead by then)
  off = mark;
  float* proj = (float*)alloc((size_t)MM*DD*4);
  float* gpre = (float*)alloc((size_t)MM*DD*4);
  u16* zbf  = (u16*)alloc((size_t)MM*DD*2);
  u16* g1   = (u16*)alloc((size_t)MM*128*2);
  float* ffa  = (float*)alloc((size_t)1024*DFF*4);
  u16* ffh  = (u16*)alloc((size_t)MM*DFF*2);

  dim3 blk(256);
  auto CVT = [&](const float* s, u16* d, int n){
    cvt_bf16<<<dim3((n/4+255)/256), blk, 0, stream>>>(s, d, n);
  };
  CVT(qw, qwb, DD*DD); CVT(kw, kwb, DD*DD); CVT(vw, vwb, DD*DD); CVT(ow, owb, DD*DD);
  CVT(fw1, fw1b, DFF*DD); CVT(fw3, fw3b, DFF*DD); CVT(fw2, fw2b, DD*DFF);
  CVT(x, xbf, MM*DD);
  cvt_split<<<dim3((DD*DD/4+255)/256), blk, 0, stream>>>(sw, swhi, swlo, DD*DD);
  pad_cvt<<<dim3((128*DD+255)/256), blk, 0, stream>>>(aupw, aupwb, 64, DD, 128, DD);
  pad_cvt<<<dim3((DD*128+255)/256), blk, 0, stream>>>(adnw, adnwb, DD, 64, DD, 128);
  pad_cvt<<<dim3((128*DD+255)/256), blk, 0, stream>>>(betw, betwb, 8, DD, 128, DD);
  pad_cvt<<<dim3((128*DD+255)/256), blk, 0, stream>>>(u1w, u1wb, 64, DD, 128, DD);
  pad_cvt<<<dim3((DD*128+255)/256), blk, 0, stream>>>(u2w, u2wb, DD, 64, DD, 128);
  pad_f32<<<dim3(1), blk, 0, stream>>>(aupb, aupbp, 64, 128);
  pad_f32<<<dim3(1), blk, 0, stream>>>(betb, betbp, 8, 128);
  pad_f32<<<dim3(1), blk, 0, stream>>>(u1b, u1bp, 64, 128);

  // norm + conv + silu
  row_rms<<<dim3(MM), blk, 0, stream>>>(x, invr);
  conv_silu_k<<<dim3(MM), blk, 0, stream>>>(x, invr, nin, cw, cb, hbf, hlo);

  dim3 gMN(MM/128, DD/128);
  dim3 gM128(MM/128, 1);
  // q, k, v
  gemm_bt<0><<<gMN, blk, 0, stream>>>(hbf, qwb, qb, nullptr, nullptr, nullptr, MM, DD, DD);
  gemm_bt<0><<<gMN, blk, 0, stream>>>(hbf, kwb, kb, nullptr, nullptr, nullptr, MM, DD, DD);
  gemm_bt<0><<<gMN, blk, 0, stream>>>(hbf, vwb, vb, nullptr, nullptr, nullptr, MM, DD, DD);
  // drive in split-bf16 (3 passes) for spike-threshold accuracy
  gemm_bt<0><<<gMN, blk, 0, stream>>>(hbf, swhi, db, nullptr, nullptr, nullptr, MM, DD, DD);
  gemm_bt<1><<<gMN, blk, 0, stream>>>(hbf, swlo, db, nullptr, nullptr, nullptr, MM, DD, DD);
  gemm_bt<1><<<gMN, blk, 0, stream>>>(hlo, swhi, db, nullptr, nullptr, nullptr, MM, DD, DD);
  // beta base [M,128] (cols 0..7 used)
  gemm_bt<0><<<gM128, blk, 0, stream>>>(hbf, betwb, bbase, nullptr, betbp, nullptr, MM, 128, DD);
  // alpha base: silu(h@up+b) @ down + b
  gemm_bt<2><<<gM128, blk, 0, stream>>>(hbf, aupwb, nullptr, gsm, aupbp, nullptr, MM, 128, DD);
  gemm_bt<0><<<gMN, blk, 0, stream>>>(gsm, adnwb, abase, nullptr, adnb, nullptr, MM, DD, 128);

  qk_norm<<<dim3(MM*HH/4), blk, 0, stream>>>(qb, kb);
  spike_prep<<<dim3(BB*HH), dim3(64), 0, stream>>>(db, abase, bbase, aspk, bspk, mem0, abase, bscale);
  scan_k<<<dim3(BB*HH*8), blk, 0, stream>>>(qb, kb, vb, abase, bscale, st0, yatt);
  head_norm_k<<<dim3(MM*HH/4), blk, 0, stream>>>(yatt, hnw, yattb);

  // out proj, gate, combine
  gemm_bt<0><<<gMN, blk, 0, stream>>>(yattb, owb, proj, nullptr, nullptr, nullptr, MM, DD, DD);
  gemm_bt<2><<<gM128, blk, 0, stream>>>(xbf, u1wb, nullptr, g1, u1bp, nullptr, MM, 128, DD);
  gemm_bt<0><<<gMN, blk, 0, stream>>>(g1, u2wb, gpre, nullptr, u2b, nullptr, MM, DD, 128);
  gate_comb<<<dim3(MM*DD/1024), blk, 0, stream>>>(x, proj, gpre, out);

  // FFN
  row_rms<<<dim3(MM), blk, 0, stream>>>(out, invr);
  zscale<<<dim3(MM), blk, 0, stream>>>(out, invr, ffnw, zbf);
  for (int c=0; c<4; ++c) {
    const u16* zc = zbf + (size_t)c*1024*DD;
    dim3 gC(1024/128, DFF/128);
    gemm_bt<0><<<gC, blk, 0, stream>>>(zc, fw1b, ffa, nullptr, nullptr, nullptr, 1024, DFF, DD);
    gemm_bt<3><<<gC, blk, 0, stream>>>(zc, fw3b, nullptr, ffh + (size_t)c*1024*DFF, nullptr, ffa, 1024, DFF, DD);
  }
  gemm_bt<1><<<gMN, blk, 0, stream>>>(ffh, fw2b, out, nullptr, nullptr, nullptr, MM, DD, DFF);
}

// Round 6
// 1062.656 us; speedup vs baseline: 1.1861x; 1.0891x over previous
//
#include <hip/hip_runtime.h>
#include <hip/hip_bf16.h>
#include <stdint.h>

#define DEV static __device__ __forceinline__

typedef float f32x4 __attribute__((ext_vector_type(4)));
typedef short bf16x8 __attribute__((ext_vector_type(8)));
typedef float accf4 __attribute__((ext_vector_type(4)));
typedef unsigned short u16;
typedef unsigned int u32;
typedef unsigned long long u64;
typedef u16 u16x4 __attribute__((ext_vector_type(4)));

#define BB 4
#define TT 1024
#define DD 1024
#define HH 8
#define DKK 128
#define DVV 128
#define MM (BB*TT)
#define DFF 4096

DEV u16 f2b(float f){
  union { float f; u32 u; } v; v.f = f;
  u32 r = (v.u + 0x7fffu + ((v.u >> 16) & 1u)) >> 16;
  return (u16)r;
}
DEV float b2f(u16 h){
  union { u32 u; float f; } v; v.u = ((u32)h) << 16;
  return v.f;
}
DEV float sigm(float x){ return 1.f / (1.f + __expf(-x)); }
DEV float silu_f(float x){ return x / (1.f + __expf(-x)); }

DEV void gl_lds16(const void* g, void* l){
  __builtin_amdgcn_global_load_lds(
      (const __attribute__((address_space(1))) void*)g,
      (__attribute__((address_space(3))) void*)l, 16, 0, 0);
}

// ---- DPP cross-lane adds (VALU pipe, ~4cy latency each; no LDS traffic) ----
template<int CTRL>
DEV float dpp_add(float x){
  union { float f; int i; } u; u.f = x;
  int y = __builtin_amdgcn_update_dpp(0, u.i, CTRL, 0xf, 0xf, true);
  union { int i; float f; } w; w.i = y;
  return x + w.f;
}
// sum over 16-lane DPP row; all 16 lanes end with the full sum
DEV float red16(float x){
  x = dpp_add<0xB1>(x);  // quad_perm [1,0,3,2]  (xor 1)
  x = dpp_add<0x4E>(x);  // quad_perm [2,3,0,1]  (xor 2)
  x = dpp_add<0x141>(x); // row_half_mirror      (pairs 4-groups)
  x = dpp_add<0x140>(x); // row_mirror           (pairs 8-groups)
  return x;
}
// sum over full wave64; lane 63 ends with the full sum
DEV float red64_last(float x){
  x = red16(x);
  x = dpp_add<0x142>(x); // row_bcast15
  x = dpp_add<0x143>(x); // row_bcast31
  return x;
}

// ---------------- GEMM: C[M,N] = A[M,K](bf16) * B[N,K](bf16)^T ---------------
// OP 0: C=acc(+bias)   OP 1: C+=acc   OP 2: Cb=bf16(silu(acc+bias))
// OP 3: Cb=bf16(silu(aux)*acc)
template<int OP>
__global__ __launch_bounds__(256) void gemm_bt(
    const u16* __restrict__ A, const u16* __restrict__ Bm,
    float* __restrict__ C, u16* __restrict__ Cb,
    const float* __restrict__ bias, const float* __restrict__ aux,
    int M, int N, int K)
{
  __shared__ u16 lsA[128*64];
  __shared__ u16 lsB[128*64];
  const int tid = threadIdx.x;
  const int bm = blockIdx.x, bn = blockIdx.y;
  const int wid = tid >> 6, lane = tid & 63;
  const int wr = wid >> 1, wc = wid & 1;
  const int fr = lane & 15, fq = lane >> 4;
  accf4 acc[4][4];
#pragma unroll
  for (int i=0;i<4;i++)
#pragma unroll
    for (int j=0;j<4;j++) acc[i][j] = (accf4)0.f;

  const int srow = tid >> 3;
  const int sk = (tid & 7) * 8;
  const u16* aP = A + (size_t)(bm*128 + srow) * K + sk;
  const u16* bP = Bm + (size_t)(bn*128 + srow) * K + sk;
  char* lA = (char*)lsA + tid*16;
  char* lB = (char*)lsB + tid*16;

  for (int kt = 0; kt < K; kt += 64) {
#pragma unroll
    for (int it=0; it<4; ++it) {
      gl_lds16(aP + (size_t)it*32*K + kt, lA + it*4096);
      gl_lds16(bP + (size_t)it*32*K + kt, lB + it*4096);
    }
    asm volatile("s_waitcnt vmcnt(0)" ::: "memory");
    __syncthreads();
#pragma unroll
    for (int ks=0; ks<2; ++ks) {
      bf16x8 av[4], bv[4];
#pragma unroll
      for (int i=0;i<4;i++)
        av[i] = *(const bf16x8*)&lsA[(wr*64 + i*16 + fr)*64 + ks*32 + fq*8];
#pragma unroll
      for (int j=0;j<4;j++)
        bv[j] = *(const bf16x8*)&lsB[(wc*64 + j*16 + fr)*64 + ks*32 + fq*8];
#pragma unroll
      for (int i=0;i<4;i++)
#pragma unroll
        for (int j=0;j<4;j++)
          acc[i][j] = __builtin_amdgcn_mfma_f32_16x16x32_bf16(av[i], bv[j], acc[i][j], 0, 0, 0);
    }
    __syncthreads();
  }

#pragma unroll
  for (int i=0;i<4;i++) {
    const int r0 = bm*128 + wr*64 + i*16 + fq*4;
#pragma unroll
    for (int j=0;j<4;j++) {
      const int c = bn*128 + wc*64 + j*16 + fr;
#pragma unroll
      for (int rr=0; rr<4; ++rr) {
        const size_t idx = (size_t)(r0+rr)*N + c;
        float v = acc[i][j][rr];
        if (OP == 0) { if (bias) v += bias[c]; C[idx] = v; }
        if (OP == 1) { C[idx] += v; }
        if (OP == 2) { v += bias[c]; Cb[idx] = f2b(silu_f(v)); }
        if (OP == 3) { Cb[idx] = f2b(silu_f(aux[idx]) * v); }
      }
    }
  }
}

// ---------------- conversions ----------------
__global__ void cvt_bf16(const float* __restrict__ s, u16* __restrict__ d, int n){
  int i = blockIdx.x*256 + threadIdx.x;
  if (i*4 < n) {
    f32x4 v = *(const f32x4*)(s + (size_t)i*4);
    u16x4 o; o.x=f2b(v.x); o.y=f2b(v.y); o.z=f2b(v.z); o.w=f2b(v.w);
    *(u16x4*)(d + (size_t)i*4) = o;
  }
}
__global__ void cvt_split(const float* __restrict__ s, u16* __restrict__ hi, u16* __restrict__ lo, int n){
  int i = blockIdx.x*256 + threadIdx.x;
  if (i*4 < n) {
    f32x4 v = *(const f32x4*)(s + (size_t)i*4);
    u16x4 h, l;
    h.x=f2b(v.x); h.y=f2b(v.y); h.z=f2b(v.z); h.w=f2b(v.w);
    l.x=f2b(v.x-b2f(h.x)); l.y=f2b(v.y-b2f(h.y)); l.z=f2b(v.z-b2f(h.z)); l.w=f2b(v.w-b2f(h.w));
    *(u16x4*)(hi + (size_t)i*4) = h;
    *(u16x4*)(lo + (size_t)i*4) = l;
  }
}
__global__ void pad_cvt(const float* __restrict__ s, u16* __restrict__ d,
                        int sr, int sc, int dr, int dc){
  int i = blockIdx.x*256 + threadIdx.x;
  if (i < dr*dc) {
    int r = i/dc, c = i%dc;
    float v = (r<sr && c<sc) ? s[(size_t)r*sc+c] : 0.f;
    d[i] = f2b(v);
  }
}
__global__ void pad_f32(const float* __restrict__ s, float* __restrict__ d, int sn, int dn){
  int i = blockIdx.x*256 + threadIdx.x;
  if (i < dn) d[i] = (i < sn) ? s[i] : 0.f;
}

// ---------------- row RMS (D=1024): invr[m] = 1/sqrt(mean(x^2)+eps) --------
__global__ __launch_bounds__(256) void row_rms(const float* __restrict__ x, float* __restrict__ invr){
  int m = blockIdx.x, tid = threadIdx.x;
  f32x4 v = *(const f32x4*)(x + (size_t)m*DD + tid*4);
  float s = v.x*v.x + v.y*v.y + v.z*v.z + v.w*v.w;
#pragma unroll
  for (int msk=1; msk<64; msk<<=1) s += __shfl_xor(s, msk);
  __shared__ float ws[4];
  if ((tid&63)==0) ws[tid>>6] = s;
  __syncthreads();
  if (tid==0) invr[m] = 1.f / sqrtf((ws[0]+ws[1]+ws[2]+ws[3])*(1.f/DD) + 1e-6f);
}

// ---------------- norm + causal depthwise conv + silu -> bf16 hi/lo --------
__global__ __launch_bounds__(256) void conv_silu_k(
    const float* __restrict__ x, const float* __restrict__ invr,
    const float* __restrict__ nw, const float* __restrict__ cw, const float* __restrict__ cb,
    u16* __restrict__ hbf, u16* __restrict__ hlo)
{
  int m = blockIdx.x, tid = threadIdx.x;
  int b = m >> 10, t = m & 1023;
  int d4 = tid * 4;
  f32x4 acc = *(const f32x4*)(cb + d4);
  f32x4 nwv = *(const f32x4*)(nw + d4);
  f32x4 w0 = *(const f32x4*)(cw + (size_t)(d4+0)*4);
  f32x4 w1 = *(const f32x4*)(cw + (size_t)(d4+1)*4);
  f32x4 w2 = *(const f32x4*)(cw + (size_t)(d4+2)*4);
  f32x4 w3 = *(const f32x4*)(cw + (size_t)(d4+3)*4);
#pragma unroll
  for (int j=0;j<4;j++) {
    int tt = t - 3 + j;
    if (tt >= 0) {
      int m2 = (b<<10) + tt;
      f32x4 xv = *(const f32x4*)(x + (size_t)m2*DD + d4);
      float sc = invr[m2];
      acc.x += xv.x * sc * nwv.x * w0[j];
      acc.y += xv.y * sc * nwv.y * w1[j];
      acc.z += xv.z * sc * nwv.z * w2[j];
      acc.w += xv.w * sc * nwv.w * w3[j];
    }
  }
  float h0 = silu_f(acc.x), h1 = silu_f(acc.y), h2 = silu_f(acc.z), h3 = silu_f(acc.w);
  size_t o = (size_t)m*DD + d4;
  u16x4 hv; hv.x=f2b(h0); hv.y=f2b(h1); hv.z=f2b(h2); hv.w=f2b(h3);
  u16x4 lv; lv.x=f2b(h0-b2f(hv.x)); lv.y=f2b(h1-b2f(hv.y)); lv.z=f2b(h2-b2f(hv.z)); lv.w=f2b(h3-b2f(hv.w));
  *(u16x4*)(hbf + o) = hv;
  *(u16x4*)(hlo + o) = lv;
}

// ---------------- q/k L2 normalization, per (m,h), one wave each -----------
__global__ __launch_bounds__(256) void qk_norm(float* __restrict__ q, float* __restrict__ k){
  int gw = blockIdx.x*4 + (threadIdx.x>>6);
  int lane = threadIdx.x & 63;
  size_t off = (size_t)(gw>>3)*DD + (size_t)(gw&7)*DKK;
  float q1 = q[off+lane], q2 = q[off+lane+64];
  float k1 = k[off+lane], k2 = k[off+lane+64];
  float sq = q1*q1+q2*q2, sk = k1*k1+k2*k2;
#pragma unroll
  for (int msk=1; msk<64; msk<<=1){ sq += __shfl_xor(sq,msk); sk += __shfl_xor(sk,msk); }
  float iq = 1.f/(sqrtf(sq)+1e-6f), ik = 1.f/(sqrtf(sk)+1e-6f);
  q[off+lane]=q1*iq; q[off+lane+64]=q2*iq;
  k[off+lane]=k1*ik; k[off+lane+64]=k2*ik;
}

// ---------------- headwise RMSNorm -> bf16 ---------------------------------
__global__ __launch_bounds__(256) void head_norm_k(
    const float* __restrict__ y, const float* __restrict__ w, u16* __restrict__ o)
{
  int gw = blockIdx.x*4 + (threadIdx.x>>6);
  int lane = threadIdx.x & 63;
  int h = gw & 7;
  size_t off = (size_t)(gw>>3)*DD + (size_t)h*DVV;
  float y1 = y[off+lane], y2 = y[off+lane+64];
  float s = y1*y1 + y2*y2;
#pragma unroll
  for (int msk=1; msk<64; msk<<=1) s += __shfl_xor(s,msk);
  float inv = 1.f / sqrtf(s*(1.f/DVV) + 1e-6f);
  o[off+lane]    = f2b(y1*inv*w[h*DVV+lane]);
  o[off+lane+64] = f2b(y2*inv*w[h*DVV+lane+64]);
}

// ---------------- LIF spike scan: LDS-DMA double buffer --------------------
// One wave per (b,h). Drive staged via global_load_lds (no dest VGPRs -> the
// compiler CANNOT sink it; R5 showed VGPR prefetch collapses at IR level).
// Counted s_waitcnt vmcnt keeps chunk c+1/c+2 loads in flight during compute.
// Outputs: packed spike masks (2 u64 per (bh,t)) + bscale. Alpha applied in
// the parallel alpha_apply kernel.
__global__ __launch_bounds__(64) void spike_scan(
    const float* __restrict__ dr, const float* __restrict__ bbase,
    const float* __restrict__ bspk, const float* __restrict__ mem0,
    u64* __restrict__ spk, float* __restrict__ bs)
{
  __shared__ float bufA[64*128];
  __shared__ float bufB[64*128];
  __shared__ float bb_lds[TT];
  const int bh = blockIdx.x, b = bh>>3, h = bh&7;
  const int lane = threadIdx.x;

  // stage beta-base column h (uncoalesced but tiny: 1024 scalars)
  for (int i=0;i<16;++i)
    bb_lds[i*64 + lane] = bbase[((size_t)b*TT + i*64 + lane)*128 + h];

  float m1 = mem0[bh*DKK + lane], m2 = mem0[bh*DKK + lane + 64];
  const float b1s = bspk[h*DKK+lane], b2s = bspk[h*DKK+lane+64];

  const char* drBase = (const char*)(dr + ((size_t)b*TT)*DD + (size_t)h*DKK);
  const int rowp = lane>>5, col = lane&31;      // 2 t-rows per gl_lds16
  // drain staging loads so DMA vmcnt counting starts clean
  asm volatile("s_waitcnt vmcnt(0) lgkmcnt(0)" ::: "memory");

  auto DMA = [&](int c){
    char* l = (char*)((c&1) ? bufB : bufA);
    const char* g = drBase + ((size_t)(c*64 + rowp)*DD + (size_t)col*4)*4;
#pragma unroll
    for (int j=0;j<32;++j)
      gl_lds16(g + (size_t)j*2*DD*4, l + j*1024);
  };

  auto CHUNK = [&](int c){
    const float* lf = (c&1) ? bufB : bufA;
    u32 q0=0,q1=0,q2=0,q3=0; float qss=0.f;
#pragma unroll 8
    for (int t=0;t<64;++t){
      float d1 = lf[t*128 + lane];
      float d2 = lf[t*128 + 64 + lane];
      m1 = 0.9f*m1 + d1; m2 = 0.9f*m2 + d2;
      bool p1 = m1 > 0.5f, p2 = m2 > 0.5f;
      u64 bl1 = __ballot(p1), bl2 = __ballot(p2);
      float sp1 = p1 ? 1.f : 0.f, sp2 = p2 ? 1.f : 0.f;
      m1 -= sp1*0.5f; m2 -= sp2*0.5f;
      float ss = red64_last(sp1*b1s + sp2*b2s);
      float ssv = __shfl(ss, 63);               // full sum lives in lane 63
      if (lane == t){
        q0=(u32)bl1; q1=(u32)(bl1>>32);
        q2=(u32)bl2; q3=(u32)(bl2>>32);
        qss=ssv;
      }
    }
    // lane t owns timestep c*64+t: coalesced mask store + beta
    const int tg = c*64 + lane;
    float bv = bb_lds[tg];
    bool act = (q0|q1|q2|q3) != 0u;
    float beta = act ? sigm(bv + qss) : 0.f;
    u32* sp32 = (u32*)(spk + ((size_t)bh*TT + tg)*2);
    uint4 m4; m4.x=q0; m4.y=q1; m4.z=q2; m4.w=q3;
    *(uint4*)sp32 = m4;
    bs[((size_t)b*TT + tg)*HH + h] = beta;
  };

  DMA(0); DMA(1);
  for (int c=0; c<16; ++c){
    if (c == 0)       asm volatile("s_waitcnt vmcnt(32)" ::: "memory");
    else if (c < 15)  asm volatile("s_waitcnt vmcnt(34)" ::: "memory");
    else              asm volatile("s_waitcnt vmcnt(2)"  ::: "memory");
    CHUNK(c);
    if (c+2 < 16) DMA(c+2);
  }
}

// ---------------- alpha = sigm(a_base + a_spike * spike_bit), in place -----
__global__ __launch_bounds__(256) void alpha_apply(
    float* __restrict__ a, const u64* __restrict__ spk,
    const float* __restrict__ aspk)
{
  const int m = blockIdx.x, d4 = threadIdx.x*4;
  const int b = m >> 10, t = m & 1023;
  const int h = d4 >> 7, dkh = d4 & 127;
  const u64 mask = spk[(((size_t)(b*8+h))*TT + t)*2 + (dkh>>6)];
  const int sh = dkh & 63;
  f32x4 av = *(const f32x4*)(a + (size_t)m*DD + d4);
  f32x4 sv = *(const f32x4*)(aspk + h*DKK + dkh);
  f32x4 o;
  o.x = sigm(av.x + (((mask>>(sh+0))&1ull) ? sv.x : 0.f));
  o.y = sigm(av.y + (((mask>>(sh+1))&1ull) ? sv.y : 0.f));
  o.z = sigm(av.z + (((mask>>(sh+2))&1ull) ? sv.z : 0.f));
  o.w = sigm(av.w + (((mask>>(sh+3))&1ull) ? sv.w : 0.f));
  *(f32x4*)(a + (size_t)m*DD + d4) = o;
}

// ---------------- gated delta-rule scan, state in registers ----------------
// grid = B*H*8 (dv split by 8 -> 256 blocks, 1 per CU), block 256:
// dkl = tid&15 (16 lanes x 8 dk = one DPP row = full DK), dvl = tid>>4.
// Lean step (~50 VALU, no transcendentals); ring-8 prefetch enforced by
// sched_barrier(0) (survives as vector loads; R4 VGPR=100 confirmed).
__global__ __launch_bounds__(256, 1) void scan_k(
    const float* __restrict__ q, const float* __restrict__ k, const float* __restrict__ v,
    const float* __restrict__ al, const float* __restrict__ bs,
    const float* __restrict__ s0p, float* __restrict__ y)
{
  const int bx = blockIdx.x;
  const int bh = bx >> 3, dvb = bx & 7;
  const int b = bh >> 3, h = bh & 7;
  const int tid = threadIdx.x;
  const int dvl = tid >> 4, dkl = tid & 15;
  const int dv = dvb*16 + dvl;
  const int dk0 = dkl*8;

  float s[8];
  {
    const float* sp = s0p + ((size_t)bh*DKK + dk0) * DVV + dv;
#pragma unroll
    for (int i=0;i<8;i++) s[i] = sp[(size_t)i*DVV];
  }
  const size_t rbase = ((size_t)b*TT)*DD + (size_t)h*DKK;
  const float* kP = k  + rbase + dk0;
  const float* qP = q  + rbase + dk0;
  const float* aP = al + rbase + dk0;
  const float* vP = v  + rbase + dv;
  const float* bP = bs + (size_t)b*TT*HH + h;
  float* yP = y + rbase + dv;

  struct Buf { f32x4 kk[2], qq[2], aa[2]; float vv, bb; };
  Buf B0,B1,B2,B3,B4,B5,B6,B7;
  auto LOAD = [&](int t_, Buf& Bx){
    size_t o = (size_t)t_*DD;
    Bx.kk[0] = *(const f32x4*)(kP + o); Bx.kk[1] = *(const f32x4*)(kP + o + 4);
    Bx.qq[0] = *(const f32x4*)(qP + o); Bx.qq[1] = *(const f32x4*)(qP + o + 4);
    Bx.aa[0] = *(const f32x4*)(aP + o); Bx.aa[1] = *(const f32x4*)(aP + o + 4);
    Bx.vv = vP[o];
    Bx.bb = bP[(size_t)t_*HH];
  };
  auto STEP = [&](const Buf& Bx, int t_){
    float pp = 0.f, pp2 = 0.f;
#pragma unroll
    for (int i=0;i<2;i++)
#pragma unroll
      for (int e=0;e<4;e++){
        float sv = s[i*4+e] * Bx.aa[i][e];
        s[i*4+e] = sv;
        if (e < 2) pp += sv * Bx.kk[i][e]; else pp2 += sv * Bx.kk[i][e];
      }
    pp = red16(pp + pp2);
    float err = Bx.bb * (Bx.vv - pp);
    float oo = 0.f, oo2 = 0.f;
#pragma unroll
    for (int i=0;i<2;i++)
#pragma unroll
      for (int e=0;e<4;e++){
        float sv = s[i*4+e] + Bx.kk[i][e] * err;
        s[i*4+e] = sv;
        if (e < 2) oo += sv * Bx.qq[i][e]; else oo2 += sv * Bx.qq[i][e];
      }
    oo = red16(oo + oo2);           // output only: off the recurrence chain
    if (dkl == 0) yP[(size_t)t_*DD] = oo;
  };

#define SBAR __builtin_amdgcn_sched_barrier(0)
  LOAD(0,B0); LOAD(1,B1); LOAD(2,B2); LOAD(3,B3);
  LOAD(4,B4); LOAD(5,B5); LOAD(6,B6);
  SBAR;
  for (int t=0; t<TT; t+=8){
    LOAD(t+ 7 < TT ? t+ 7 : TT-1, B7); SBAR; STEP(B0, t);   SBAR;
    LOAD(t+ 8 < TT ? t+ 8 : TT-1, B0); SBAR; STEP(B1, t+1); SBAR;
    LOAD(t+ 9 < TT ? t+ 9 : TT-1, B1); SBAR; STEP(B2, t+2); SBAR;
    LOAD(t+10 < TT ? t+10 : TT-1, B2); SBAR; STEP(B3, t+3); SBAR;
    LOAD(t+11 < TT ? t+11 : TT-1, B3); SBAR; STEP(B4, t+4); SBAR;
    LOAD(t+12 < TT ? t+12 : TT-1, B4); SBAR; STEP(B5, t+5); SBAR;
    LOAD(t+13 < TT ? t+13 : TT-1, B5); SBAR; STEP(B6, t+6); SBAR;
    LOAD(t+14 < TT ? t+14 : TT-1, B6); SBAR; STEP(B7, t+7); SBAR;
  }
#undef SBAR
}

// ---------------- y1 = x + proj*sigmoid(gate_pre) --------------------------
__global__ __launch_bounds__(256) void gate_comb(
    const float* __restrict__ x, const float* __restrict__ p,
    const float* __restrict__ g, float* __restrict__ y1)
{
  size_t i = ((size_t)blockIdx.x*256 + threadIdx.x)*4;
  f32x4 xv = *(const f32x4*)(x+i);
  f32x4 pv = *(const f32x4*)(p+i);
  f32x4 gv = *(const f32x4*)(g+i);
  f32x4 o;
  o.x = xv.x + pv.x * sigm(gv.x);
  o.y = xv.y + pv.y * sigm(gv.y);
  o.z = xv.z + pv.z * sigm(gv.z);
  o.w = xv.w + pv.w * sigm(gv.w);
  *(f32x4*)(y1+i) = o;
}

// ---------------- z = bf16(y1 * invr * ff_norm_w) --------------------------
__global__ __launch_bounds__(256) void zscale(
    const float* __restrict__ y1, const float* __restrict__ invr,
    const float* __restrict__ w, u16* __restrict__ z)
{
  int m = blockIdx.x; int d4 = threadIdx.x*4;
  float sc = invr[m];
  f32x4 v = *(const f32x4*)(y1 + (size_t)m*DD + d4);
  f32x4 wv = *(const f32x4*)(w + d4);
  u16x4 o; o.x=f2b(v.x*sc*wv.x); o.y=f2b(v.y*sc*wv.y); o.z=f2b(v.z*sc*wv.z); o.w=f2b(v.w*sc*wv.w);
  *(u16x4*)(z + (size_t)m*DD + d4) = o;
}

extern "C" void kernel_launch(void* const* d_in, const int* in_sizes, int n_in,
                              void* d_out, int out_size, void* d_ws, size_t ws_size,
                              hipStream_t stream)
{
  (void)in_sizes; (void)n_in; (void)out_size; (void)ws_size;
  const float* x    = (const float*)d_in[0];
  const float* st0  = (const float*)d_in[1];
  const float* mem0 = (const float*)d_in[2];
  const float* nin  = (const float*)d_in[3];
  const float* cw   = (const float*)d_in[4];
  const float* cb   = (const float*)d_in[5];
  const float* qw   = (const float*)d_in[6];
  const float* kw   = (const float*)d_in[7];
  const float* vw   = (const float*)d_in[8];
  const float* ow   = (const float*)d_in[9];
  const float* sw   = (const float*)d_in[10];
  const float* aupw = (const float*)d_in[11];
  const float* aupb = (const float*)d_in[12];
  const float* adnw = (const float*)d_in[13];
  const float* adnb = (const float*)d_in[14];
  const float* aspk = (const float*)d_in[15];
  const float* betw = (const float*)d_in[16];
  const float* betb = (const float*)d_in[17];
  const float* bspk = (const float*)d_in[18];
  const float* hnw  = (const float*)d_in[19];
  const float* u1w  = (const float*)d_in[20];
  const float* u1b  = (const float*)d_in[21];
  const float* u2w  = (const float*)d_in[22];
  const float* u2b  = (const float*)d_in[23];
  const float* ffnw = (const float*)d_in[24];
  const float* fw1  = (const float*)d_in[25];
  const float* fw3  = (const float*)d_in[26];
  const float* fw2  = (const float*)d_in[27];
  float* out = (float*)d_out;

  char* wsb = (char*)d_ws;
  size_t off = 0;
  auto alloc = [&](size_t bytes)->char*{
    off = (off + 255) & ~(size_t)255;
    char* p = wsb + off; off += bytes; return p;
  };

  // persistent
  u16* qwb  = (u16*)alloc((size_t)DD*DD*2);
  u16* kwb  = (u16*)alloc((size_t)DD*DD*2);
  u16* vwb  = (u16*)alloc((size_t)DD*DD*2);
  u16* owb  = (u16*)alloc((size_t)DD*DD*2);
  u16* swhi = (u16*)alloc((size_t)DD*DD*2);
  u16* swlo = (u16*)alloc((size_t)DD*DD*2);
  u16* fw1b = (u16*)alloc((size_t)DFF*DD*2);
  u16* fw3b = (u16*)alloc((size_t)DFF*DD*2);
  u16* fw2b = (u16*)alloc((size_t)DD*DFF*2);
  u16* aupwb= (u16*)alloc((size_t)128*DD*2);
  u16* adnwb= (u16*)alloc((size_t)DD*128*2);
  u16* betwb= (u16*)alloc((size_t)128*DD*2);
  u16* u1wb = (u16*)alloc((size_t)128*DD*2);
  u16* u2wb = (u16*)alloc((size_t)DD*128*2);
  float* aupbp = (float*)alloc(128*4);
  float* betbp = (float*)alloc(128*4);
  float* u1bp  = (float*)alloc(128*4);
  u16* xbf  = (u16*)alloc((size_t)MM*DD*2);
  float* yatt  = (float*)alloc((size_t)MM*DD*4);
  u16* yattb = (u16*)alloc((size_t)MM*DD*2);
  float* invr  = (float*)alloc((size_t)MM*4);

  // early region
  size_t mark = off;
  u16* hbf = (u16*)alloc((size_t)MM*DD*2);
  u16* hlo = (u16*)alloc((size_t)MM*DD*2);
  float* qb = (float*)alloc((size_t)MM*DD*4);
  float* kb = (float*)alloc((size_t)MM*DD*4);
  float* vb = (float*)alloc((size_t)MM*DD*4);
  float* db = (float*)alloc((size_t)MM*DD*4);
  float* abase = (float*)alloc((size_t)MM*DD*4);   // becomes alpha in place
  float* bbase = (float*)alloc((size_t)MM*128*4);
  float* bscale= (float*)alloc((size_t)MM*8*4);
  u64* spk = (u64*)alloc((size_t)BB*HH*TT*2*8);
  u16* gsm  = (u16*)alloc((size_t)MM*128*2);
  // late region (aliases early; early all dead by then)
  off = mark;
  float* proj = (float*)alloc((size_t)MM*DD*4);
  float* gpre = (float*)alloc((size_t)MM*DD*4);
  u16* zbf  = (u16*)alloc((size_t)MM*DD*2);
  u16* g1   = (u16*)alloc((size_t)MM*128*2);
  float* ffa  = (float*)alloc((size_t)1024*DFF*4);
  u16* ffh  = (u16*)alloc((size_t)MM*DFF*2);

  dim3 blk(256);
  auto CVT = [&](const float* s, u16* d, int n){
    cvt_bf16<<<dim3((n/4+255)/256), blk, 0, stream>>>(s, d, n);
  };
  CVT(qw, qwb, DD*DD); CVT(kw, kwb, DD*DD); CVT(vw, vwb, DD*DD); CVT(ow, owb, DD*DD);
  CVT(fw1, fw1b, DFF*DD); CVT(fw3, fw3b, DFF*DD); CVT(fw2, fw2b, DD*DFF);
  CVT(x, xbf, MM*DD);
  cvt_split<<<dim3((DD*DD/4+255)/256), blk, 0, stream>>>(sw, swhi, swlo, DD*DD);
  pad_cvt<<<dim3((128*DD+255)/256), blk, 0, stream>>>(aupw, aupwb, 64, DD, 128, DD);
  pad_cvt<<<dim3((DD*128+255)/256), blk, 0, stream>>>(adnw, adnwb, DD, 64, DD, 128);
  pad_cvt<<<dim3((128*DD+255)/256), blk, 0, stream>>>(betw, betwb, 8, DD, 128, DD);
  pad_cvt<<<dim3((128*DD+255)/256), blk, 0, stream>>>(u1w, u1wb, 64, DD, 128, DD);
  pad_cvt<<<dim3((DD*128+255)/256), blk, 0, stream>>>(u2w, u2wb, DD, 64, DD, 128);
  pad_f32<<<dim3(1), blk, 0, stream>>>(aupb, aupbp, 64, 128);
  pad_f32<<<dim3(1), blk, 0, stream>>>(betb, betbp, 8, 128);
  pad_f32<<<dim3(1), blk, 0, stream>>>(u1b, u1bp, 64, 128);

  // norm + conv + silu
  row_rms<<<dim3(MM), blk, 0, stream>>>(x, invr);
  conv_silu_k<<<dim3(MM), blk, 0, stream>>>(x, invr, nin, cw, cb, hbf, hlo);

  dim3 gMN(MM/128, DD/128);
  dim3 gM128(MM/128, 1);
  // q, k, v
  gemm_bt<0><<<gMN, blk, 0, stream>>>(hbf, qwb, qb, nullptr, nullptr, nullptr, MM, DD, DD);
  gemm_bt<0><<<gMN, blk, 0, stream>>>(hbf, kwb, kb, nullptr, nullptr, nullptr, MM, DD, DD);
  gemm_bt<0><<<gMN, blk, 0, stream>>>(hbf, vwb, vb, nullptr, nullptr, nullptr, MM, DD, DD);
  // drive in split-bf16 (3 passes) for spike-threshold accuracy
  gemm_bt<0><<<gMN, blk, 0, stream>>>(hbf, swhi, db, nullptr, nullptr, nullptr, MM, DD, DD);
  gemm_bt<1><<<gMN, blk, 0, stream>>>(hbf, swlo, db, nullptr, nullptr, nullptr, MM, DD, DD);
  gemm_bt<1><<<gMN, blk, 0, stream>>>(hlo, swhi, db, nullptr, nullptr, nullptr, MM, DD, DD);
  // beta base [M,128] (cols 0..7 used)
  gemm_bt<0><<<gM128, blk, 0, stream>>>(hbf, betwb, bbase, nullptr, betbp, nullptr, MM, 128, DD);
  // LIF spike scan (needs db, bbase)
  spike_scan<<<dim3(BB*HH), dim3(64), 0, stream>>>(db, bbase, bspk, mem0, spk, bscale);
  // alpha base: silu(h@up+b) @ down + b
  gemm_bt<2><<<gM128, blk, 0, stream>>>(hbf, aupwb, nullptr, gsm, aupbp, nullptr, MM, 128, DD);
  gemm_bt<0><<<gMN, blk, 0, stream>>>(gsm, adnwb, abase, nullptr, adnb, nullptr, MM, DD, 128);
  // alpha = sigm(abase + aspk*spike), in place
  alpha_apply<<<dim3(MM), blk, 0, stream>>>(abase, spk, aspk);

  qk_norm<<<dim3(MM*HH/4), blk, 0, stream>>>(qb, kb);
  scan_k<<<dim3(BB*HH*8), blk, 0, stream>>>(qb, kb, vb, abase, bscale, st0, yatt);
  head_norm_k<<<dim3(MM*HH/4), blk, 0, stream>>>(yatt, hnw, yattb);

  // out proj, gate, combine
  gemm_bt<0><<<gMN, blk, 0, stream>>>(yattb, owb, proj, nullptr, nullptr, nullptr, MM, DD, DD);
  gemm_bt<2><<<gM128, blk, 0, stream>>>(xbf, u1wb, nullptr, g1, u1bp, nullptr, MM, 128, DD);
  gemm_bt<0><<<gMN, blk, 0, stream>>>(g1, u2wb, gpre, nullptr, u2b, nullptr, MM, DD, 128);
  gate_comb<<<dim3(MM*DD/1024), blk, 0, stream>>>(x, proj, gpre, out);

  // FFN
  row_rms<<<dim3(MM), blk, 0, stream>>>(out, invr);
  zscale<<<dim3(MM), blk, 0, stream>>>(out, invr, ffnw, zbf);
  for (int c=0; c<4; ++c) {
    const u16* zc = zbf + (size_t)c*1024*DD;
    dim3 gC(1024/128, DFF/128);
    gemm_bt<0><<<gC, blk, 0, stream>>>(zc, fw1b, ffa, nullptr, nullptr, nullptr, 1024, DFF, DD);
    gemm_bt<3><<<gC, blk, 0, stream>>>(zc, fw3b, nullptr, ffh + (size_t)c*1024*DFF, nullptr, ffa, 1024, DFF, DD);
  }
  gemm_bt<1><<<gMN, blk, 0, stream>>>(ffh, fw2b, out, nullptr, nullptr, nullptr, MM, DD, DFF);
}

// Round 7
// 1034.598 us; speedup vs baseline: 1.2182x; 1.0271x over previous
//
#include <hip/hip_runtime.h>
#include <hip/hip_bf16.h>
#include <stdint.h>

#define DEV static __device__ __forceinline__

typedef float f32x4 __attribute__((ext_vector_type(4)));
typedef short bf16x8 __attribute__((ext_vector_type(8)));
typedef float accf4 __attribute__((ext_vector_type(4)));
typedef unsigned short u16;
typedef unsigned int u32;
typedef unsigned long long u64;
typedef u16 u16x4 __attribute__((ext_vector_type(4)));

#define BB 4
#define TT 1024
#define DD 1024
#define HH 8
#define DKK 128
#define DVV 128
#define MM (BB*TT)
#define DFF 4096

DEV u16 f2b(float f){
  union { float f; u32 u; } v; v.f = f;
  u32 r = (v.u + 0x7fffu + ((v.u >> 16) & 1u)) >> 16;
  return (u16)r;
}
DEV float b2f(u16 h){
  union { u32 u; float f; } v; v.u = ((u32)h) << 16;
  return v.f;
}
DEV float sigm(float x){ return 1.f / (1.f + __expf(-x)); }
DEV float silu_f(float x){ return x / (1.f + __expf(-x)); }

DEV void gl_lds16(const void* g, void* l){
  __builtin_amdgcn_global_load_lds(
      (const __attribute__((address_space(1))) void*)g,
      (__attribute__((address_space(3))) void*)l, 16, 0, 0);
}

// ---- DPP cross-lane adds (VALU pipe, ~4cy latency each; no LDS traffic) ----
template<int CTRL>
DEV float dpp_add(float x){
  union { float f; int i; } u; u.f = x;
  int y = __builtin_amdgcn_update_dpp(0, u.i, CTRL, 0xf, 0xf, true);
  union { int i; float f; } w; w.i = y;
  return x + w.f;
}
// sum over 16-lane DPP row; all 16 lanes end with the full sum
DEV float red16(float x){
  x = dpp_add<0xB1>(x);  // quad_perm [1,0,3,2]  (xor 1)
  x = dpp_add<0x4E>(x);  // quad_perm [2,3,0,1]  (xor 2)
  x = dpp_add<0x141>(x); // row_half_mirror      (pairs 4-groups)
  x = dpp_add<0x140>(x); // row_mirror           (pairs 8-groups)
  return x;
}
// sum over full wave64; lane 63 ends with the full sum
DEV float red64_last(float x){
  x = red16(x);
  x = dpp_add<0x142>(x); // row_bcast15
  x = dpp_add<0x143>(x); // row_bcast31
  return x;
}

// ---------------- GEMM: C[M,N] = A[M,K](bf16) * B[N,K](bf16)^T ---------------
// 2-phase double-buffered LDS (T3 minimum recipe): STAGE(next) issued BEFORE
// compute(cur); single vmcnt(0)+barrier per K-step so stage latency hides
// under the 32 MFMAs. lda/ldb allow K-concatenated operands.
// OP 0: C=acc(+bias)   OP 1: C+=acc   OP 2: Cb=bf16(silu(acc+bias))
// OP 3: Cb=bf16(silu(aux)*acc)
template<int OP>
__global__ __launch_bounds__(256) void gemm_bt(
    const u16* __restrict__ A, const u16* __restrict__ Bm,
    float* __restrict__ C, u16* __restrict__ Cb,
    const float* __restrict__ bias, const float* __restrict__ aux,
    int M, int N, int K, int lda, int ldb)
{
  __shared__ u16 lsA[2][128*64];
  __shared__ u16 lsB[2][128*64];
  const int tid = threadIdx.x;
  const int bm = blockIdx.x, bn = blockIdx.y;
  const int wid = tid >> 6, lane = tid & 63;
  const int wr = wid >> 1, wc = wid & 1;
  const int fr = lane & 15, fq = lane >> 4;
  accf4 acc[4][4];
#pragma unroll
  for (int i=0;i<4;i++)
#pragma unroll
    for (int j=0;j<4;j++) acc[i][j] = (accf4)0.f;

  const int srow = tid >> 3;
  const int sk = (tid & 7) * 8;
  const u16* aP = A + (size_t)(bm*128 + srow) * lda + sk;
  const u16* bP = Bm + (size_t)(bn*128 + srow) * ldb + sk;

  auto STAGE = [&](int buf, int t){
    char* lA = (char*)lsA[buf] + tid*16;
    char* lB = (char*)lsB[buf] + tid*16;
    const u16* a = aP + (size_t)t*64;
    const u16* b = bP + (size_t)t*64;
#pragma unroll
    for (int it=0; it<4; ++it) {
      gl_lds16(a + (size_t)it*32*lda, lA + it*4096);
      gl_lds16(b + (size_t)it*32*ldb, lB + it*4096);
    }
  };

  const int nk = K >> 6;
  STAGE(0, 0);
  asm volatile("s_waitcnt vmcnt(0)" ::: "memory");
  __syncthreads();
  int cur = 0;
  for (int t = 0; t < nk; ++t) {
    if (t + 1 < nk) STAGE(cur ^ 1, t + 1);
    const u16* la = lsA[cur];
    const u16* lb = lsB[cur];
#pragma unroll
    for (int ks=0; ks<2; ++ks) {
      bf16x8 av[4], bv[4];
#pragma unroll
      for (int i=0;i<4;i++)
        av[i] = *(const bf16x8*)&la[(wr*64 + i*16 + fr)*64 + ks*32 + fq*8];
#pragma unroll
      for (int j=0;j<4;j++)
        bv[j] = *(const bf16x8*)&lb[(wc*64 + j*16 + fr)*64 + ks*32 + fq*8];
#pragma unroll
      for (int i=0;i<4;i++)
#pragma unroll
        for (int j=0;j<4;j++)
          acc[i][j] = __builtin_amdgcn_mfma_f32_16x16x32_bf16(av[i], bv[j], acc[i][j], 0, 0, 0);
    }
    asm volatile("s_waitcnt vmcnt(0)" ::: "memory");
    __syncthreads();
    cur ^= 1;
  }

#pragma unroll
  for (int i=0;i<4;i++) {
    const int r0 = bm*128 + wr*64 + i*16 + fq*4;
#pragma unroll
    for (int j=0;j<4;j++) {
      const int c = bn*128 + wc*64 + j*16 + fr;
#pragma unroll
      for (int rr=0; rr<4; ++rr) {
        const size_t idx = (size_t)(r0+rr)*N + c;
        float v = acc[i][j][rr];
        if (OP == 0) { if (bias) v += bias[c]; C[idx] = v; }
        if (OP == 1) { C[idx] += v; }
        if (OP == 2) { v += bias[c]; Cb[idx] = f2b(silu_f(v)); }
        if (OP == 3) { Cb[idx] = f2b(silu_f(aux[idx]) * v); }
      }
    }
  }
}

// ---------------- conversions ----------------
__global__ void cvt_bf16(const float* __restrict__ s, u16* __restrict__ d, int n){
  int i = blockIdx.x*256 + threadIdx.x;
  if (i*4 < n) {
    f32x4 v = *(const f32x4*)(s + (size_t)i*4);
    u16x4 o; o.x=f2b(v.x); o.y=f2b(v.y); o.z=f2b(v.z); o.w=f2b(v.w);
    *(u16x4*)(d + (size_t)i*4) = o;
  }
}
// split f32 -> [lo | hi] K-concatenated rows of width 2048 (row = i/1024)
__global__ void cvt_split(const float* __restrict__ s, u16* __restrict__ cat, int n){
  int i = blockIdx.x*256 + threadIdx.x;
  if (i*4 < n) {
    f32x4 v = *(const f32x4*)(s + (size_t)i*4);
    int r = (i*4) >> 10, c = (i*4) & 1023;
    u16x4 h, l;
    h.x=f2b(v.x); h.y=f2b(v.y); h.z=f2b(v.z); h.w=f2b(v.w);
    l.x=f2b(v.x-b2f(h.x)); l.y=f2b(v.y-b2f(h.y)); l.z=f2b(v.z-b2f(h.z)); l.w=f2b(v.w-b2f(h.w));
    *(u16x4*)(cat + (size_t)r*2048 + c) = l;
    *(u16x4*)(cat + (size_t)r*2048 + 1024 + c) = h;
  }
}
__global__ void pad_cvt(const float* __restrict__ s, u16* __restrict__ d,
                        int sr, int sc, int dr, int dc){
  int i = blockIdx.x*256 + threadIdx.x;
  if (i < dr*dc) {
    int r = i/dc, c = i%dc;
    float v = (r<sr && c<sc) ? s[(size_t)r*sc+c] : 0.f;
    d[i] = f2b(v);
  }
}
__global__ void pad_f32(const float* __restrict__ s, float* __restrict__ d, int sn, int dn){
  int i = blockIdx.x*256 + threadIdx.x;
  if (i < dn) d[i] = (i < sn) ? s[i] : 0.f;
}

// ---------------- row RMS (D=1024): invr[m] = 1/sqrt(mean(x^2)+eps) --------
__global__ __launch_bounds__(256) void row_rms(const float* __restrict__ x, float* __restrict__ invr){
  int m = blockIdx.x, tid = threadIdx.x;
  f32x4 v = *(const f32x4*)(x + (size_t)m*DD + tid*4);
  float s = v.x*v.x + v.y*v.y + v.z*v.z + v.w*v.w;
#pragma unroll
  for (int msk=1; msk<64; msk<<=1) s += __shfl_xor(s, msk);
  __shared__ float ws[4];
  if ((tid&63)==0) ws[tid>>6] = s;
  __syncthreads();
  if (tid==0) invr[m] = 1.f / sqrtf((ws[0]+ws[1]+ws[2]+ws[3])*(1.f/DD) + 1e-6f);
}

// ---------------- norm + causal depthwise conv + silu -> bf16 hi|lo cat ----
__global__ __launch_bounds__(256) void conv_silu_k(
    const float* __restrict__ x, const float* __restrict__ invr,
    const float* __restrict__ nw, const float* __restrict__ cw, const float* __restrict__ cb,
    u16* __restrict__ hcat)
{
  int m = blockIdx.x, tid = threadIdx.x;
  int b = m >> 10, t = m & 1023;
  int d4 = tid * 4;
  f32x4 acc = *(const f32x4*)(cb + d4);
  f32x4 nwv = *(const f32x4*)(nw + d4);
  f32x4 w0 = *(const f32x4*)(cw + (size_t)(d4+0)*4);
  f32x4 w1 = *(const f32x4*)(cw + (size_t)(d4+1)*4);
  f32x4 w2 = *(const f32x4*)(cw + (size_t)(d4+2)*4);
  f32x4 w3 = *(const f32x4*)(cw + (size_t)(d4+3)*4);
#pragma unroll
  for (int j=0;j<4;j++) {
    int tt = t - 3 + j;
    if (tt >= 0) {
      int m2 = (b<<10) + tt;
      f32x4 xv = *(const f32x4*)(x + (size_t)m2*DD + d4);
      float sc = invr[m2];
      acc.x += xv.x * sc * nwv.x * w0[j];
      acc.y += xv.y * sc * nwv.y * w1[j];
      acc.z += xv.z * sc * nwv.z * w2[j];
      acc.w += xv.w * sc * nwv.w * w3[j];
    }
  }
  float h0 = silu_f(acc.x), h1 = silu_f(acc.y), h2 = silu_f(acc.z), h3 = silu_f(acc.w);
  size_t o = (size_t)m*2048 + d4;
  u16x4 hv; hv.x=f2b(h0); hv.y=f2b(h1); hv.z=f2b(h2); hv.w=f2b(h3);
  u16x4 lv; lv.x=f2b(h0-b2f(hv.x)); lv.y=f2b(h1-b2f(hv.y)); lv.z=f2b(h2-b2f(hv.z)); lv.w=f2b(h3-b2f(hv.w));
  *(u16x4*)(hcat + o) = hv;          // cols 0..1023  = h (bf16 hi)
  *(u16x4*)(hcat + o + 1024) = lv;   // cols 1024..2047 = h lo residue
}

// ---------------- q/k L2 normalization, per (m,h), one wave each -----------
__global__ __launch_bounds__(256) void qk_norm(float* __restrict__ q, float* __restrict__ k){
  int gw = blockIdx.x*4 + (threadIdx.x>>6);
  int lane = threadIdx.x & 63;
  size_t off = (size_t)(gw>>3)*DD + (size_t)(gw&7)*DKK;
  float q1 = q[off+lane], q2 = q[off+lane+64];
  float k1 = k[off+lane], k2 = k[off+lane+64];
  float sq = q1*q1+q2*q2, sk = k1*k1+k2*k2;
#pragma unroll
  for (int msk=1; msk<64; msk<<=1){ sq += __shfl_xor(sq,msk); sk += __shfl_xor(sk,msk); }
  float iq = 1.f/(sqrtf(sq)+1e-6f), ik = 1.f/(sqrtf(sk)+1e-6f);
  q[off+lane]=q1*iq; q[off+lane+64]=q2*iq;
  k[off+lane]=k1*ik; k[off+lane+64]=k2*ik;
}

// ---------------- headwise RMSNorm -> bf16 ---------------------------------
__global__ __launch_bounds__(256) void head_norm_k(
    const float* __restrict__ y, const float* __restrict__ w, u16* __restrict__ o)
{
  int gw = blockIdx.x*4 + (threadIdx.x>>6);
  int lane = threadIdx.x & 63;
  int h = gw & 7;
  size_t off = (size_t)(gw>>3)*DD + (size_t)h*DVV;
  float y1 = y[off+lane], y2 = y[off+lane+64];
  float s = y1*y1 + y2*y2;
#pragma unroll
  for (int msk=1; msk<64; msk<<=1) s += __shfl_xor(s,msk);
  float inv = 1.f / sqrtf(s*(1.f/DVV) + 1e-6f);
  o[off+lane]    = f2b(y1*inv*w[h*DVV+lane]);
  o[off+lane+64] = f2b(y2*inv*w[h*DVV+lane+64]);
}

// ---------------- LIF spike scan: LDS-DMA double buffer --------------------
// One wave per (b,h). Drive staged via global_load_lds (no dest VGPRs -> the
// compiler CANNOT sink it). Counted s_waitcnt vmcnt keeps chunk c+1/c+2 loads
// in flight during compute. Outputs packed spike masks + bscale.
__global__ __launch_bounds__(64) void spike_scan(
    const float* __restrict__ dr, const float* __restrict__ bbase,
    const float* __restrict__ bspk, const float* __restrict__ mem0,
    u64* __restrict__ spk, float* __restrict__ bs)
{
  __shared__ float bufA[64*128];
  __shared__ float bufB[64*128];
  __shared__ float bb_lds[TT];
  const int bh = blockIdx.x, b = bh>>3, h = bh&7;
  const int lane = threadIdx.x;

  for (int i=0;i<16;++i)
    bb_lds[i*64 + lane] = bbase[((size_t)b*TT + i*64 + lane)*128 + h];

  float m1 = mem0[bh*DKK + lane], m2 = mem0[bh*DKK + lane + 64];
  const float b1s = bspk[h*DKK+lane], b2s = bspk[h*DKK+lane+64];

  const char* drBase = (const char*)(dr + ((size_t)b*TT)*DD + (size_t)h*DKK);
  const int rowp = lane>>5, col = lane&31;
  asm volatile("s_waitcnt vmcnt(0) lgkmcnt(0)" ::: "memory");

  auto DMA = [&](int c){
    char* l = (char*)((c&1) ? bufB : bufA);
    const char* g = drBase + ((size_t)(c*64 + rowp)*DD + (size_t)col*4)*4;
#pragma unroll
    for (int j=0;j<32;++j)
      gl_lds16(g + (size_t)j*2*DD*4, l + j*1024);
  };

  auto CHUNK = [&](int c){
    const float* lf = (c&1) ? bufB : bufA;
    u32 q0=0,q1=0,q2=0,q3=0; float qss=0.f;
#pragma unroll 8
    for (int t=0;t<64;++t){
      float d1 = lf[t*128 + lane];
      float d2 = lf[t*128 + 64 + lane];
      m1 = 0.9f*m1 + d1; m2 = 0.9f*m2 + d2;
      bool p1 = m1 > 0.5f, p2 = m2 > 0.5f;
      u64 bl1 = __ballot(p1), bl2 = __ballot(p2);
      float sp1 = p1 ? 1.f : 0.f, sp2 = p2 ? 1.f : 0.f;
      m1 -= sp1*0.5f; m2 -= sp2*0.5f;
      float ss = red64_last(sp1*b1s + sp2*b2s);
      float ssv = __shfl(ss, 63);
      if (lane == t){
        q0=(u32)bl1; q1=(u32)(bl1>>32);
        q2=(u32)bl2; q3=(u32)(bl2>>32);
        qss=ssv;
      }
    }
    const int tg = c*64 + lane;
    float bv = bb_lds[tg];
    bool act = (q0|q1|q2|q3) != 0u;
    float beta = act ? sigm(bv + qss) : 0.f;
    u32* sp32 = (u32*)(spk + ((size_t)bh*TT + tg)*2);
    uint4 m4; m4.x=q0; m4.y=q1; m4.z=q2; m4.w=q3;
    *(uint4*)sp32 = m4;
    bs[((size_t)b*TT + tg)*HH + h] = beta;
  };

  DMA(0); DMA(1);
  for (int c=0; c<16; ++c){
    if (c == 0)       asm volatile("s_waitcnt vmcnt(32)" ::: "memory");
    else if (c < 15)  asm volatile("s_waitcnt vmcnt(34)" ::: "memory");
    else              asm volatile("s_waitcnt vmcnt(2)"  ::: "memory");
    CHUNK(c);
    if (c+2 < 16) DMA(c+2);
  }
}

// ---------------- alpha = sigm(a_base + a_spike * spike_bit), in place -----
__global__ __launch_bounds__(256) void alpha_apply(
    float* __restrict__ a, const u64* __restrict__ spk,
    const float* __restrict__ aspk)
{
  const int m = blockIdx.x, d4 = threadIdx.x*4;
  const int b = m >> 10, t = m & 1023;
  const int h = d4 >> 7, dkh = d4 & 127;
  const u64 mask = spk[(((size_t)(b*8+h))*TT + t)*2 + (dkh>>6)];
  const int sh = dkh & 63;
  f32x4 av = *(const f32x4*)(a + (size_t)m*DD + d4);
  f32x4 sv = *(const f32x4*)(aspk + h*DKK + dkh);
  f32x4 o;
  o.x = sigm(av.x + (((mask>>(sh+0))&1ull) ? sv.x : 0.f));
  o.y = sigm(av.y + (((mask>>(sh+1))&1ull) ? sv.y : 0.f));
  o.z = sigm(av.z + (((mask>>(sh+2))&1ull) ? sv.z : 0.f));
  o.w = sigm(av.w + (((mask>>(sh+3))&1ull) ? sv.w : 0.f));
  *(f32x4*)(a + (size_t)m*DD + d4) = o;
}

// ---------------- gated delta-rule scan, state in registers ----------------
__global__ __launch_bounds__(256, 1) void scan_k(
    const float* __restrict__ q, const float* __restrict__ k, const float* __restrict__ v,
    const float* __restrict__ al, const float* __restrict__ bs,
    const float* __restrict__ s0p, float* __restrict__ y)
{
  const int bx = blockIdx.x;
  const int bh = bx >> 3, dvb = bx & 7;
  const int b = bh >> 3, h = bh & 7;
  const int tid = threadIdx.x;
  const int dvl = tid >> 4, dkl = tid & 15;
  const int dv = dvb*16 + dvl;
  const int dk0 = dkl*8;

  float s[8];
  {
    const float* sp = s0p + ((size_t)bh*DKK + dk0) * DVV + dv;
#pragma unroll
    for (int i=0;i<8;i++) s[i] = sp[(size_t)i*DVV];
  }
  const size_t rbase = ((size_t)b*TT)*DD + (size_t)h*DKK;
  const float* kP = k  + rbase + dk0;
  const float* qP = q  + rbase + dk0;
  const float* aP = al + rbase + dk0;
  const float* vP = v  + rbase + dv;
  const float* bP = bs + (size_t)b*TT*HH + h;
  float* yP = y + rbase + dv;

  struct Buf { f32x4 kk[2], qq[2], aa[2]; float vv, bb; };
  Buf B0,B1,B2,B3,B4,B5,B6,B7;
  auto LOAD = [&](int t_, Buf& Bx){
    size_t o = (size_t)t_*DD;
    Bx.kk[0] = *(const f32x4*)(kP + o); Bx.kk[1] = *(const f32x4*)(kP + o + 4);
    Bx.qq[0] = *(const f32x4*)(qP + o); Bx.qq[1] = *(const f32x4*)(qP + o + 4);
    Bx.aa[0] = *(const f32x4*)(aP + o); Bx.aa[1] = *(const f32x4*)(aP + o + 4);
    Bx.vv = vP[o];
    Bx.bb = bP[(size_t)t_*HH];
  };
  auto STEP = [&](const Buf& Bx, int t_){
    float pp = 0.f, pp2 = 0.f;
#pragma unroll
    for (int i=0;i<2;i++)
#pragma unroll
      for (int e=0;e<4;e++){
        float sv = s[i*4+e] * Bx.aa[i][e];
        s[i*4+e] = sv;
        if (e < 2) pp += sv * Bx.kk[i][e]; else pp2 += sv * Bx.kk[i][e];
      }
    pp = red16(pp + pp2);
    float err = Bx.bb * (Bx.vv - pp);
    float oo = 0.f, oo2 = 0.f;
#pragma unroll
    for (int i=0;i<2;i++)
#pragma unroll
      for (int e=0;e<4;e++){
        float sv = s[i*4+e] + Bx.kk[i][e] * err;
        s[i*4+e] = sv;
        if (e < 2) oo += sv * Bx.qq[i][e]; else oo2 += sv * Bx.qq[i][e];
      }
    oo = red16(oo + oo2);
    if (dkl == 0) yP[(size_t)t_*DD] = oo;
  };

#define SBAR __builtin_amdgcn_sched_barrier(0)
  LOAD(0,B0); LOAD(1,B1); LOAD(2,B2); LOAD(3,B3);
  LOAD(4,B4); LOAD(5,B5); LOAD(6,B6);
  SBAR;
  for (int t=0; t<TT; t+=8){
    LOAD(t+ 7 < TT ? t+ 7 : TT-1, B7); SBAR; STEP(B0, t);   SBAR;
    LOAD(t+ 8 < TT ? t+ 8 : TT-1, B0); SBAR; STEP(B1, t+1); SBAR;
    LOAD(t+ 9 < TT ? t+ 9 : TT-1, B1); SBAR; STEP(B2, t+2); SBAR;
    LOAD(t+10 < TT ? t+10 : TT-1, B2); SBAR; STEP(B3, t+3); SBAR;
    LOAD(t+11 < TT ? t+11 : TT-1, B3); SBAR; STEP(B4, t+4); SBAR;
    LOAD(t+12 < TT ? t+12 : TT-1, B4); SBAR; STEP(B5, t+5); SBAR;
    LOAD(t+13 < TT ? t+13 : TT-1, B5); SBAR; STEP(B6, t+6); SBAR;
    LOAD(t+14 < TT ? t+14 : TT-1, B6); SBAR; STEP(B7, t+7); SBAR;
  }
#undef SBAR
}

// ---------------- y1 = x + proj*sigmoid(gate_pre) --------------------------
__global__ __launch_bounds__(256) void gate_comb(
    const float* __restrict__ x, const float* __restrict__ p,
    const float* __restrict__ g, float* __restrict__ y1)
{
  size_t i = ((size_t)blockIdx.x*256 + threadIdx.x)*4;
  f32x4 xv = *(const f32x4*)(x+i);
  f32x4 pv = *(const f32x4*)(p+i);
  f32x4 gv = *(const f32x4*)(g+i);
  f32x4 o;
  o.x = xv.x + pv.x * sigm(gv.x);
  o.y = xv.y + pv.y * sigm(gv.y);
  o.z = xv.z + pv.z * sigm(gv.z);
  o.w = xv.w + pv.w * sigm(gv.w);
  *(f32x4*)(y1+i) = o;
}

// ---------------- z = bf16(y1 * invr * ff_norm_w) --------------------------
__global__ __launch_bounds__(256) void zscale(
    const float* __restrict__ y1, const float* __restrict__ invr,
    const float* __restrict__ w, u16* __restrict__ z)
{
  int m = blockIdx.x; int d4 = threadIdx.x*4;
  float sc = invr[m];
  f32x4 v = *(const f32x4*)(y1 + (size_t)m*DD + d4);
  f32x4 wv = *(const f32x4*)(w + d4);
  u16x4 o; o.x=f2b(v.x*sc*wv.x); o.y=f2b(v.y*sc*wv.y); o.z=f2b(v.z*sc*wv.z); o.w=f2b(v.w*sc*wv.w);
  *(u16x4*)(z + (size_t)m*DD + d4) = o;
}

extern "C" void kernel_launch(void* const* d_in, const int* in_sizes, int n_in,
                              void* d_out, int out_size, void* d_ws, size_t ws_size,
                              hipStream_t stream)
{
  (void)in_sizes; (void)n_in; (void)out_size; (void)ws_size;
  const float* x    = (const float*)d_in[0];
  const float* st0  = (const float*)d_in[1];
  const float* mem0 = (const float*)d_in[2];
  const float* nin  = (const float*)d_in[3];
  const float* cw   = (const float*)d_in[4];
  const float* cb   = (const float*)d_in[5];
  const float* qw   = (const float*)d_in[6];
  const float* kw   = (const float*)d_in[7];
  const float* vw   = (const float*)d_in[8];
  const float* ow   = (const float*)d_in[9];
  const float* sw   = (const float*)d_in[10];
  const float* aupw = (const float*)d_in[11];
  const float* aupb = (const float*)d_in[12];
  const float* adnw = (const float*)d_in[13];
  const float* adnb = (const float*)d_in[14];
  const float* aspk = (const float*)d_in[15];
  const float* betw = (const float*)d_in[16];
  const float* betb = (const float*)d_in[17];
  const float* bspk = (const float*)d_in[18];
  const float* hnw  = (const float*)d_in[19];
  const float* u1w  = (const float*)d_in[20];
  const float* u1b  = (const float*)d_in[21];
  const float* u2w  = (const float*)d_in[22];
  const float* u2b  = (const float*)d_in[23];
  const float* ffnw = (const float*)d_in[24];
  const float* fw1  = (const float*)d_in[25];
  const float* fw3  = (const float*)d_in[26];
  const float* fw2  = (const float*)d_in[27];
  float* out = (float*)d_out;

  char* wsb = (char*)d_ws;
  size_t off = 0;
  auto alloc = [&](size_t bytes)->char*{
    off = (off + 255) & ~(size_t)255;
    char* p = wsb + off; off += bytes; return p;
  };

  // persistent
  u16* qwb  = (u16*)alloc((size_t)DD*DD*2);
  u16* kwb  = (u16*)alloc((size_t)DD*DD*2);
  u16* vwb  = (u16*)alloc((size_t)DD*DD*2);
  u16* owb  = (u16*)alloc((size_t)DD*DD*2);
  u16* swcat= (u16*)alloc((size_t)DD*2048*2);  // [lo | hi] K-concat
  u16* fw1b = (u16*)alloc((size_t)DFF*DD*2);
  u16* fw3b = (u16*)alloc((size_t)DFF*DD*2);
  u16* fw2b = (u16*)alloc((size_t)DD*DFF*2);
  u16* aupwb= (u16*)alloc((size_t)128*DD*2);
  u16* adnwb= (u16*)alloc((size_t)DD*128*2);
  u16* betwb= (u16*)alloc((size_t)128*DD*2);
  u16* u1wb = (u16*)alloc((size_t)128*DD*2);
  u16* u2wb = (u16*)alloc((size_t)DD*128*2);
  float* aupbp = (float*)alloc(128*4);
  float* betbp = (float*)alloc(128*4);
  float* u1bp  = (float*)alloc(128*4);
  u16* xbf  = (u16*)alloc((size_t)MM*DD*2);
  float* yatt  = (float*)alloc((size_t)MM*DD*4);
  u16* yattb = (u16*)alloc((size_t)MM*DD*2);
  float* invr  = (float*)alloc((size_t)MM*4);

  // early region
  size_t mark = off;
  u16* hcat = (u16*)alloc((size_t)MM*2048*2);  // [h_bf16 | h_lo] K-concat
  float* qb = (float*)alloc((size_t)MM*DD*4);
  float* kb = (float*)alloc((size_t)MM*DD*4);
  float* vb = (float*)alloc((size_t)MM*DD*4);
  float* db = (float*)alloc((size_t)MM*DD*4);
  float* abase = (float*)alloc((size_t)MM*DD*4);   // becomes alpha in place
  float* bbase = (float*)alloc((size_t)MM*128*4);
  float* bscale= (float*)alloc((size_t)MM*8*4);
  u64* spk = (u64*)alloc((size_t)BB*HH*TT*2*8);
  u16* gsm  = (u16*)alloc((size_t)MM*128*2);
  // late region (aliases early; early all dead by then)
  off = mark;
  float* proj = (float*)alloc((size_t)MM*DD*4);
  float* gpre = (float*)alloc((size_t)MM*DD*4);
  u16* zbf  = (u16*)alloc((size_t)MM*DD*2);
  u16* g1   = (u16*)alloc((size_t)MM*128*2);
  float* ffa  = (float*)alloc((size_t)1024*DFF*4);
  u16* ffh  = (u16*)alloc((size_t)MM*DFF*2);

  dim3 blk(256);
  auto CVT = [&](const float* s, u16* d, int n){
    cvt_bf16<<<dim3((n/4+255)/256), blk, 0, stream>>>(s, d, n);
  };
  CVT(qw, qwb, DD*DD); CVT(kw, kwb, DD*DD); CVT(vw, vwb, DD*DD); CVT(ow, owb, DD*DD);
  CVT(fw1, fw1b, DFF*DD); CVT(fw3, fw3b, DFF*DD); CVT(fw2, fw2b, DD*DFF);
  CVT(x, xbf, MM*DD);
  cvt_split<<<dim3((DD*DD/4+255)/256), blk, 0, stream>>>(sw, swcat, DD*DD);
  pad_cvt<<<dim3((128*DD+255)/256), blk, 0, stream>>>(aupw, aupwb, 64, DD, 128, DD);
  pad_cvt<<<dim3((DD*128+255)/256), blk, 0, stream>>>(adnw, adnwb, DD, 64, DD, 128);
  pad_cvt<<<dim3((128*DD+255)/256), blk, 0, stream>>>(betw, betwb, 8, DD, 128, DD);
  pad_cvt<<<dim3((128*DD+255)/256), blk, 0, stream>>>(u1w, u1wb, 64, DD, 128, DD);
  pad_cvt<<<dim3((DD*128+255)/256), blk, 0, stream>>>(u2w, u2wb, DD, 64, DD, 128);
  pad_f32<<<dim3(1), blk, 0, stream>>>(aupb, aupbp, 64, 128);
  pad_f32<<<dim3(1), blk, 0, stream>>>(betb, betbp, 8, 128);
  pad_f32<<<dim3(1), blk, 0, stream>>>(u1b, u1bp, 64, 128);

  // norm + conv + silu
  row_rms<<<dim3(MM), blk, 0, stream>>>(x, invr);
  conv_silu_k<<<dim3(MM), blk, 0, stream>>>(x, invr, nin, cw, cb, hcat);

  dim3 gMN(MM/128, DD/128);
  dim3 gM128(MM/128, 1);
  // q, k, v  (A = hcat cols 0..1023, lda=2048)
  gemm_bt<0><<<gMN, blk, 0, stream>>>(hcat, qwb, qb, nullptr, nullptr, nullptr, MM, DD, DD, 2048, DD);
  gemm_bt<0><<<gMN, blk, 0, stream>>>(hcat, kwb, kb, nullptr, nullptr, nullptr, MM, DD, DD, 2048, DD);
  gemm_bt<0><<<gMN, blk, 0, stream>>>(hcat, vwb, vb, nullptr, nullptr, nullptr, MM, DD, DD, 2048, DD);
  // drive split-bf16: db = hbf@swhi  then  db += [hbf|hlo]@[swlo|swhi] (K=2048)
  gemm_bt<0><<<gMN, blk, 0, stream>>>(hcat, swcat+1024, db, nullptr, nullptr, nullptr, MM, DD, DD, 2048, 2048);
  gemm_bt<1><<<gMN, blk, 0, stream>>>(hcat, swcat, db, nullptr, nullptr, nullptr, MM, DD, 2048, 2048, 2048);
  // beta base [M,128] (cols 0..7 used)
  gemm_bt<0><<<gM128, blk, 0, stream>>>(hcat, betwb, bbase, nullptr, betbp, nullptr, MM, 128, DD, 2048, DD);
  // LIF spike scan (needs db, bbase)
  spike_scan<<<dim3(BB*HH), dim3(64), 0, stream>>>(db, bbase, bspk, mem0, spk, bscale);
  // alpha base: silu(h@up+b) @ down + b
  gemm_bt<2><<<gM128, blk, 0, stream>>>(hcat, aupwb, nullptr, gsm, aupbp, nullptr, MM, 128, DD, 2048, DD);
  gemm_bt<0><<<gMN, blk, 0, stream>>>(gsm, adnwb, abase, nullptr, adnb, nullptr, MM, DD, 128, 128, 128);
  // alpha = sigm(abase + aspk*spike), in place
  alpha_apply<<<dim3(MM), blk, 0, stream>>>(abase, spk, aspk);

  qk_norm<<<dim3(MM*HH/4), blk, 0, stream>>>(qb, kb);
  scan_k<<<dim3(BB*HH*8), blk, 0, stream>>>(qb, kb, vb, abase, bscale, st0, yatt);
  head_norm_k<<<dim3(MM*HH/4), blk, 0, stream>>>(yatt, hnw, yattb);

  // out proj, gate, combine
  gemm_bt<0><<<gMN, blk, 0, stream>>>(yattb, owb, proj, nullptr, nullptr, nullptr, MM, DD, DD, DD, DD);
  gemm_bt<2><<<gM128, blk, 0, stream>>>(xbf, u1wb, nullptr, g1, u1bp, nullptr, MM, 128, DD, DD, DD);
  gemm_bt<0><<<gMN, blk, 0, stream>>>(g1, u2wb, gpre, nullptr, u2b, nullptr, MM, DD, 128, 128, 128);
  gate_comb<<<dim3(MM*DD/1024), blk, 0, stream>>>(x, proj, gpre, out);

  // FFN
  row_rms<<<dim3(MM), blk, 0, stream>>>(out, invr);
  zscale<<<dim3(MM), blk, 0, stream>>>(out, invr, ffnw, zbf);
  for (int c=0; c<4; ++c) {
    const u16* zc = zbf + (size_t)c*1024*DD;
    dim3 gC(1024/128, DFF/128);
    gemm_bt<0><<<gC, blk, 0, stream>>>(zc, fw1b, ffa, nullptr, nullptr, nullptr, 1024, DFF, DD, DD, DD);
    gemm_bt<3><<<gC, blk, 0, stream>>>(zc, fw3b, nullptr, ffh + (size_t)c*1024*DFF, nullptr, ffa, 1024, DFF, DD, DD, DD);
  }
  gemm_bt<1><<<gMN, blk, 0, stream>>>(ffh, fw2b, out, nullptr, nullptr, nullptr, MM, DD, DFF, DFF, DFF);
}

// Round 8
// 907.007 us; speedup vs baseline: 1.3896x; 1.1407x over previous
//
#include <hip/hip_runtime.h>
#include <hip/hip_bf16.h>
#include <stdint.h>

#define DEV static __device__ __forceinline__

typedef float f32x4 __attribute__((ext_vector_type(4)));
typedef short bf16x8 __attribute__((ext_vector_type(8)));
typedef float accf4 __attribute__((ext_vector_type(4)));
typedef unsigned short u16;
typedef unsigned int u32;
typedef unsigned long long u64;
typedef u16 u16x4 __attribute__((ext_vector_type(4)));

#define BB 4
#define TT 1024
#define DD 1024
#define HH 8
#define DKK 128
#define DVV 128
#define MM (BB*TT)
#define DFF 4096
#define SKQ 4096   // qkvd row stride

DEV u16 f2b(float f){
  union { float f; u32 u; } v; v.f = f;
  u32 r = (v.u + 0x7fffu + ((v.u >> 16) & 1u)) >> 16;
  return (u16)r;
}
DEV float b2f(u16 h){
  union { u32 u; float f; } v; v.u = ((u32)h) << 16;
  return v.f;
}
DEV float sigm(float x){ return 1.f / (1.f + __expf(-x)); }
DEV float silu_f(float x){ return x / (1.f + __expf(-x)); }

DEV void gl_lds16(const void* g, void* l){
  __builtin_amdgcn_global_load_lds(
      (const __attribute__((address_space(1))) void*)g,
      (__attribute__((address_space(3))) void*)l, 16, 0, 0);
}

// ---- DPP cross-lane adds ----
template<int CTRL>
DEV float dpp_add(float x){
  union { float f; int i; } u; u.f = x;
  int y = __builtin_amdgcn_update_dpp(0, u.i, CTRL, 0xf, 0xf, true);
  union { int i; float f; } w; w.i = y;
  return x + w.f;
}
DEV float red16(float x){
  x = dpp_add<0xB1>(x);
  x = dpp_add<0x4E>(x);
  x = dpp_add<0x141>(x);
  x = dpp_add<0x140>(x);
  return x;
}
DEV float red64_last(float x){
  x = red16(x);
  x = dpp_add<0x142>(x);
  x = dpp_add<0x143>(x);
  return x;
}

// ---------------- GEMM: C[M,N] = A * B^T, 2-phase double-buffered LDS -------
// OP 0: C=acc(+bias)   OP 1: C+=acc   OP 2: Cb=bf16(silu(acc+bias))
template<int OP>
__global__ __launch_bounds__(256) void gemm_bt(
    const u16* __restrict__ A, const u16* __restrict__ Bm,
    float* __restrict__ C, u16* __restrict__ Cb,
    const float* __restrict__ bias,
    int N, int K, int lda, int ldb, int ldc)
{
  __shared__ u16 lsA[2][128*64];
  __shared__ u16 lsB[2][128*64];
  const int tid = threadIdx.x;
  const int bm = blockIdx.x, bn = blockIdx.y;
  const int wid = tid >> 6, lane = tid & 63;
  const int wr = wid >> 1, wc = wid & 1;
  const int fr = lane & 15, fq = lane >> 4;
  accf4 acc[4][4];
#pragma unroll
  for (int i=0;i<4;i++)
#pragma unroll
    for (int j=0;j<4;j++) acc[i][j] = (accf4)0.f;

  const int srow = tid >> 3;
  const int sk = (tid & 7) * 8;
  const u16* aP = A + (size_t)(bm*128 + srow) * lda + sk;
  const u16* bP = Bm + (size_t)(bn*128 + srow) * ldb + sk;

  auto STAGE = [&](int buf, int t){
    char* lA = (char*)lsA[buf] + tid*16;
    char* lB = (char*)lsB[buf] + tid*16;
    const u16* a = aP + (size_t)t*64;
    const u16* b = bP + (size_t)t*64;
#pragma unroll
    for (int it=0; it<4; ++it) {
      gl_lds16(a + (size_t)it*32*lda, lA + it*4096);
      gl_lds16(b + (size_t)it*32*ldb, lB + it*4096);
    }
  };

  const int nk = K >> 6;
  STAGE(0, 0);
  asm volatile("s_waitcnt vmcnt(0)" ::: "memory");
  __syncthreads();
  int cur = 0;
  for (int t = 0; t < nk; ++t) {
    if (t + 1 < nk) STAGE(cur ^ 1, t + 1);
    const u16* la = lsA[cur];
    const u16* lb = lsB[cur];
#pragma unroll
    for (int ks=0; ks<2; ++ks) {
      bf16x8 av[4], bv[4];
#pragma unroll
      for (int i=0;i<4;i++)
        av[i] = *(const bf16x8*)&la[(wr*64 + i*16 + fr)*64 + ks*32 + fq*8];
#pragma unroll
      for (int j=0;j<4;j++)
        bv[j] = *(const bf16x8*)&lb[(wc*64 + j*16 + fr)*64 + ks*32 + fq*8];
#pragma unroll
      for (int i=0;i<4;i++)
#pragma unroll
        for (int j=0;j<4;j++)
          acc[i][j] = __builtin_amdgcn_mfma_f32_16x16x32_bf16(av[i], bv[j], acc[i][j], 0, 0, 0);
    }
    asm volatile("s_waitcnt vmcnt(0)" ::: "memory");
    __syncthreads();
    cur ^= 1;
  }

#pragma unroll
  for (int i=0;i<4;i++) {
    const int r0 = bm*128 + wr*64 + i*16 + fq*4;
#pragma unroll
    for (int j=0;j<4;j++) {
      const int c = bn*128 + wc*64 + j*16 + fr;
#pragma unroll
      for (int rr=0; rr<4; ++rr) {
        const size_t idx = (size_t)(r0+rr)*ldc + c;
        float v = acc[i][j][rr];
        if (OP == 0) { if (bias) v += bias[c]; C[idx] = v; }
        if (OP == 1) { C[idx] += v; }
        if (OP == 2) { v += bias[c]; Cb[idx] = f2b(silu_f(v)); }
      }
    }
  }
}

// ---------------- fused weight/input prep (replaces 16 tiny dispatches) ----
// Block ranges (each 4 f32->bf16 elems per thread unless noted):
//  [0,1024)qw [1024,2048)kw [2048,3072)vw [3072,4096)sw(hi+lo,3 dst)
//  [4096,5120)ow [5120,9216)fw1 [9216,13312)fw3 [13312,17408)fw2
//  [17408,21504)x [21504,21632)aupw-pad [21632,21760)adnw-pad
//  [21760,21888)betw-pad [21888,22016)u1w-pad [22016,22144)u2w-pad
//  [22144] bias pads
__global__ __launch_bounds__(256) void prep_all(
    const float* __restrict__ qw, const float* __restrict__ kw,
    const float* __restrict__ vw, const float* __restrict__ sw,
    const float* __restrict__ ow, const float* __restrict__ fw1,
    const float* __restrict__ fw3, const float* __restrict__ fw2,
    const float* __restrict__ x, const float* __restrict__ aupw,
    const float* __restrict__ adnw, const float* __restrict__ betw,
    const float* __restrict__ u1w, const float* __restrict__ u2w,
    const float* __restrict__ aupb, const float* __restrict__ betb,
    const float* __restrict__ u1b,
    u16* __restrict__ wcat4, u16* __restrict__ swcat, u16* __restrict__ owb,
    u16* __restrict__ fwcat, u16* __restrict__ fw2b, u16* __restrict__ xbf,
    u16* __restrict__ aupwb, u16* __restrict__ adnwb, u16* __restrict__ betwb,
    u16* __restrict__ u1wb, u16* __restrict__ u2wb,
    float* __restrict__ aupbp, float* __restrict__ betbp, float* __restrict__ u1bp)
{
  const int bid = blockIdx.x, tid = threadIdx.x;
  auto cvt4 = [&](const float* s, u16* d, int base){
    size_t i = ((size_t)(bid - base)*256 + tid)*4;
    f32x4 v = *(const f32x4*)(s + i);
    u16x4 o; o.x=f2b(v.x); o.y=f2b(v.y); o.z=f2b(v.z); o.w=f2b(v.w);
    *(u16x4*)(d + i) = o;
  };
  auto pad4 = [&](const float* s, u16* d, int base, int sr, int sc, int dc){
    size_t i = ((size_t)(bid - base)*256 + tid)*4;
    int r = (int)(i / dc), c = (int)(i % dc);
    u16x4 o;
#pragma unroll
    for (int e=0;e<4;e++){
      float v = (r < sr && c+e < sc) ? s[(size_t)r*sc + c + e] : 0.f;
      o[e] = f2b(v);
    }
    *(u16x4*)(d + i) = o;
  };
  if (bid < 1024)       cvt4(qw, wcat4, 0);
  else if (bid < 2048)  cvt4(kw, wcat4 + (size_t)1024*1024, 1024);
  else if (bid < 3072)  cvt4(vw, wcat4 + (size_t)2*1024*1024, 2048);
  else if (bid < 4096) {
    size_t i = ((size_t)(bid - 3072)*256 + tid)*4;
    int r = (int)(i >> 10), c = (int)(i & 1023);
    f32x4 v = *(const f32x4*)(sw + i);
    u16x4 h, l;
    h.x=f2b(v.x); h.y=f2b(v.y); h.z=f2b(v.z); h.w=f2b(v.w);
    l.x=f2b(v.x-b2f(h.x)); l.y=f2b(v.y-b2f(h.y)); l.z=f2b(v.z-b2f(h.z)); l.w=f2b(v.w-b2f(h.w));
    *(u16x4*)(wcat4 + (size_t)3*1024*1024 + i) = h;
    *(u16x4*)(swcat + (size_t)r*2048 + 1024 + c) = h;
    *(u16x4*)(swcat + (size_t)r*2048 + c) = l;
  }
  else if (bid < 5120)  cvt4(ow, owb, 4096);
  else if (bid < 9216)  cvt4(fw1, fwcat, 5120);
  else if (bid < 13312) cvt4(fw3, fwcat + (size_t)DFF*1024, 9216);
  else if (bid < 17408) cvt4(fw2, fw2b, 13312);
  else if (bid < 21504) cvt4(x, xbf, 17408);
  else if (bid < 21632) pad4(aupw, aupwb, 21504, 64, 1024, 1024);
  else if (bid < 21760) pad4(adnw, adnwb, 21632, 1024, 64, 128);
  else if (bid < 21888) pad4(betw, betwb, 21760, 8, 1024, 1024);
  else if (bid < 22016) pad4(u1w, u1wb, 21888, 64, 1024, 1024);
  else if (bid < 22144) pad4(u2w, u2wb, 22016, 1024, 64, 128);
  else if (tid < 128) {
    aupbp[tid] = tid < 64 ? aupb[tid] : 0.f;
    betbp[tid] = tid < 8  ? betb[tid] : 0.f;
    u1bp[tid]  = tid < 64 ? u1b[tid]  : 0.f;
  }
}

// ---------------- row RMS (D=1024) -----------------------------------------
__global__ __launch_bounds__(256) void row_rms(const float* __restrict__ x, float* __restrict__ invr){
  int m = blockIdx.x, tid = threadIdx.x;
  f32x4 v = *(const f32x4*)(x + (size_t)m*DD + tid*4);
  float s = v.x*v.x + v.y*v.y + v.z*v.z + v.w*v.w;
#pragma unroll
  for (int msk=1; msk<64; msk<<=1) s += __shfl_xor(s, msk);
  __shared__ float ws[4];
  if ((tid&63)==0) ws[tid>>6] = s;
  __syncthreads();
  if (tid==0) invr[m] = 1.f / sqrtf((ws[0]+ws[1]+ws[2]+ws[3])*(1.f/DD) + 1e-6f);
}

// ---------------- norm + causal conv + silu -> bf16 [hi|lo] cat ------------
__global__ __launch_bounds__(256) void conv_silu_k(
    const float* __restrict__ x, const float* __restrict__ invr,
    const float* __restrict__ nw, const float* __restrict__ cw, const float* __restrict__ cb,
    u16* __restrict__ hcat)
{
  int m = blockIdx.x, tid = threadIdx.x;
  int b = m >> 10, t = m & 1023;
  int d4 = tid * 4;
  f32x4 acc = *(const f32x4*)(cb + d4);
  f32x4 nwv = *(const f32x4*)(nw + d4);
  f32x4 w0 = *(const f32x4*)(cw + (size_t)(d4+0)*4);
  f32x4 w1 = *(const f32x4*)(cw + (size_t)(d4+1)*4);
  f32x4 w2 = *(const f32x4*)(cw + (size_t)(d4+2)*4);
  f32x4 w3 = *(const f32x4*)(cw + (size_t)(d4+3)*4);
#pragma unroll
  for (int j=0;j<4;j++) {
    int tt = t - 3 + j;
    if (tt >= 0) {
      int m2 = (b<<10) + tt;
      f32x4 xv = *(const f32x4*)(x + (size_t)m2*DD + d4);
      float sc = invr[m2];
      acc.x += xv.x * sc * nwv.x * w0[j];
      acc.y += xv.y * sc * nwv.y * w1[j];
      acc.z += xv.z * sc * nwv.z * w2[j];
      acc.w += xv.w * sc * nwv.w * w3[j];
    }
  }
  float h0 = silu_f(acc.x), h1 = silu_f(acc.y), h2 = silu_f(acc.z), h3 = silu_f(acc.w);
  size_t o = (size_t)m*2048 + d4;
  u16x4 hv; hv.x=f2b(h0); hv.y=f2b(h1); hv.z=f2b(h2); hv.w=f2b(h3);
  u16x4 lv; lv.x=f2b(h0-b2f(hv.x)); lv.y=f2b(h1-b2f(hv.y)); lv.z=f2b(h2-b2f(hv.z)); lv.w=f2b(h3-b2f(hv.w));
  *(u16x4*)(hcat + o) = hv;
  *(u16x4*)(hcat + o + 1024) = lv;
}

// ---------------- q/k L2 normalization inside qkvd (stride 4096) -----------
__global__ __launch_bounds__(256) void qk_norm(float* __restrict__ qkv){
  int gw = blockIdx.x*4 + (threadIdx.x>>6);
  int lane = threadIdx.x & 63;
  size_t off = (size_t)(gw>>3)*SKQ + (size_t)(gw&7)*DKK;
  float* q = qkv + off;
  float* k = qkv + off + 1024;
  float q1 = q[lane], q2 = q[lane+64];
  float k1 = k[lane], k2 = k[lane+64];
  float sq = q1*q1+q2*q2, sk = k1*k1+k2*k2;
#pragma unroll
  for (int msk=1; msk<64; msk<<=1){ sq += __shfl_xor(sq,msk); sk += __shfl_xor(sk,msk); }
  float iq = 1.f/(sqrtf(sq)+1e-6f), ik = 1.f/(sqrtf(sk)+1e-6f);
  q[lane]=q1*iq; q[lane+64]=q2*iq;
  k[lane]=k1*ik; k[lane+64]=k2*ik;
}

// ---------------- headwise RMSNorm -> bf16 ---------------------------------
__global__ __launch_bounds__(256) void head_norm_k(
    const float* __restrict__ y, const float* __restrict__ w, u16* __restrict__ o)
{
  int gw = blockIdx.x*4 + (threadIdx.x>>6);
  int lane = threadIdx.x & 63;
  int h = gw & 7;
  size_t off = (size_t)(gw>>3)*DD + (size_t)h*DVV;
  float y1 = y[off+lane], y2 = y[off+lane+64];
  float s = y1*y1 + y2*y2;
#pragma unroll
  for (int msk=1; msk<64; msk<<=1) s += __shfl_xor(s,msk);
  float inv = 1.f / sqrtf(s*(1.f/DVV) + 1e-6f);
  o[off+lane]    = f2b(y1*inv*w[h*DVV+lane]);
  o[off+lane+64] = f2b(y2*inv*w[h*DVV+lane+64]);
}

// ---------------- LIF spike scan: LDS-DMA double buffer --------------------
// dr = qkvd + 3072, row stride SKQ.
__global__ __launch_bounds__(64) void spike_scan(
    const float* __restrict__ dr, const float* __restrict__ bbase,
    const float* __restrict__ bspk, const float* __restrict__ mem0,
    u64* __restrict__ spk, float* __restrict__ bs)
{
  __shared__ float bufA[64*128];
  __shared__ float bufB[64*128];
  __shared__ float bb_lds[TT];
  const int bh = blockIdx.x, b = bh>>3, h = bh&7;
  const int lane = threadIdx.x;

  for (int i=0;i<16;++i)
    bb_lds[i*64 + lane] = bbase[((size_t)b*TT + i*64 + lane)*128 + h];

  float m1 = mem0[bh*DKK + lane], m2 = mem0[bh*DKK + lane + 64];
  const float b1s = bspk[h*DKK+lane], b2s = bspk[h*DKK+lane+64];

  const char* drBase = (const char*)(dr + ((size_t)b*TT)*SKQ + (size_t)h*DKK);
  const int rowp = lane>>5, col = lane&31;
  asm volatile("s_waitcnt vmcnt(0) lgkmcnt(0)" ::: "memory");

  auto DMA = [&](int c){
    char* l = (char*)((c&1) ? bufB : bufA);
    const char* g = drBase + ((size_t)(c*64 + rowp)*SKQ + (size_t)col*4)*4;
#pragma unroll
    for (int j=0;j<32;++j)
      gl_lds16(g + (size_t)j*2*SKQ*4, l + j*1024);
  };

  auto CHUNK = [&](int c){
    const float* lf = (c&1) ? bufB : bufA;
    u32 q0=0,q1=0,q2=0,q3=0; float qss=0.f;
#pragma unroll 8
    for (int t=0;t<64;++t){
      float d1 = lf[t*128 + lane];
      float d2 = lf[t*128 + 64 + lane];
      m1 = 0.9f*m1 + d1; m2 = 0.9f*m2 + d2;
      bool p1 = m1 > 0.5f, p2 = m2 > 0.5f;
      u64 bl1 = __ballot(p1), bl2 = __ballot(p2);
      float sp1 = p1 ? 1.f : 0.f, sp2 = p2 ? 1.f : 0.f;
      m1 -= sp1*0.5f; m2 -= sp2*0.5f;
      float ss = red64_last(sp1*b1s + sp2*b2s);
      float ssv = __shfl(ss, 63);
      if (lane == t){
        q0=(u32)bl1; q1=(u32)(bl1>>32);
        q2=(u32)bl2; q3=(u32)(bl2>>32);
        qss=ssv;
      }
    }
    const int tg = c*64 + lane;
    float bv = bb_lds[tg];
    bool act = (q0|q1|q2|q3) != 0u;
    float beta = act ? sigm(bv + qss) : 0.f;
    u32* sp32 = (u32*)(spk + ((size_t)bh*TT + tg)*2);
    uint4 m4; m4.x=q0; m4.y=q1; m4.z=q2; m4.w=q3;
    *(uint4*)sp32 = m4;
    bs[((size_t)b*TT + tg)*HH + h] = beta;
  };

  DMA(0); DMA(1);
  for (int c=0; c<16; ++c){
    if (c == 0)       asm volatile("s_waitcnt vmcnt(32)" ::: "memory");
    else if (c < 15)  asm volatile("s_waitcnt vmcnt(34)" ::: "memory");
    else              asm volatile("s_waitcnt vmcnt(2)"  ::: "memory");
    CHUNK(c);
    if (c+2 < 16) DMA(c+2);
  }
}

// ---------------- alpha = sigm(a_base + a_spike * spike_bit), in place -----
__global__ __launch_bounds__(256) void alpha_apply(
    float* __restrict__ a, const u64* __restrict__ spk,
    const float* __restrict__ aspk)
{
  const int m = blockIdx.x, d4 = threadIdx.x*4;
  const int b = m >> 10, t = m & 1023;
  const int h = d4 >> 7, dkh = d4 & 127;
  const u64 mask = spk[(((size_t)(b*8+h))*TT + t)*2 + (dkh>>6)];
  const int sh = dkh & 63;
  f32x4 av = *(const f32x4*)(a + (size_t)m*DD + d4);
  f32x4 sv = *(const f32x4*)(aspk + h*DKK + dkh);
  f32x4 o;
  o.x = sigm(av.x + (((mask>>(sh+0))&1ull) ? sv.x : 0.f));
  o.y = sigm(av.y + (((mask>>(sh+1))&1ull) ? sv.y : 0.f));
  o.z = sigm(av.z + (((mask>>(sh+2))&1ull) ? sv.z : 0.f));
  o.w = sigm(av.w + (((mask>>(sh+3))&1ull) ? sv.w : 0.f));
  *(f32x4*)(a + (size_t)m*DD + d4) = o;
}

// ---------------- gated delta-rule scan ------------------------------------
// q/k/v live in qkvd (row stride SKQ); alpha in abase (stride DD).
__global__ __launch_bounds__(256, 1) void scan_k(
    const float* __restrict__ qkv, const float* __restrict__ al,
    const float* __restrict__ bs, const float* __restrict__ s0p,
    float* __restrict__ y)
{
  const int bx = blockIdx.x;
  const int bh = bx >> 3, dvb = bx & 7;
  const int b = bh >> 3, h = bh & 7;
  const int tid = threadIdx.x;
  const int dvl = tid >> 4, dkl = tid & 15;
  const int dv = dvb*16 + dvl;
  const int dk0 = dkl*8;

  float s[8];
  {
    const float* sp = s0p + ((size_t)bh*DKK + dk0) * DVV + dv;
#pragma unroll
    for (int i=0;i<8;i++) s[i] = sp[(size_t)i*DVV];
  }
  const size_t rq = ((size_t)b*TT)*SKQ + (size_t)h*DKK;
  const size_t ra = ((size_t)b*TT)*DD + (size_t)h*DKK;
  const float* qP = qkv + rq + dk0;
  const float* kP = qkv + rq + 1024 + dk0;
  const float* vP = qkv + rq + 2048 + dv;
  const float* aP = al + ra + dk0;
  const float* bP = bs + (size_t)b*TT*HH + h;
  float* yP = y + ra + dv;

  struct Buf { f32x4 kk[2], qq[2], aa[2]; float vv, bb; };
  Buf B0,B1,B2,B3,B4,B5,B6,B7;
  auto LOAD = [&](int t_, Buf& Bx){
    size_t o = (size_t)t_*SKQ;
    size_t oa = (size_t)t_*DD;
    Bx.kk[0] = *(const f32x4*)(kP + o); Bx.kk[1] = *(const f32x4*)(kP + o + 4);
    Bx.qq[0] = *(const f32x4*)(qP + o); Bx.qq[1] = *(const f32x4*)(qP + o + 4);
    Bx.aa[0] = *(const f32x4*)(aP + oa); Bx.aa[1] = *(const f32x4*)(aP + oa + 4);
    Bx.vv = vP[o];
    Bx.bb = bP[(size_t)t_*HH];
  };
  auto STEP = [&](const Buf& Bx, int t_){
    float pp = 0.f, pp2 = 0.f;
#pragma unroll
    for (int i=0;i<2;i++)
#pragma unroll
      for (int e=0;e<4;e++){
        float sv = s[i*4+e] * Bx.aa[i][e];
        s[i*4+e] = sv;
        if (e < 2) pp += sv * Bx.kk[i][e]; else pp2 += sv * Bx.kk[i][e];
      }
    pp = red16(pp + pp2);
    float err = Bx.bb * (Bx.vv - pp);
    float oo = 0.f, oo2 = 0.f;
#pragma unroll
    for (int i=0;i<2;i++)
#pragma unroll
      for (int e=0;e<4;e++){
        float sv = s[i*4+e] + Bx.kk[i][e] * err;
        s[i*4+e] = sv;
        if (e < 2) oo += sv * Bx.qq[i][e]; else oo2 += sv * Bx.qq[i][e];
      }
    oo = red16(oo + oo2);
    if (dkl == 0) yP[(size_t)t_*DD] = oo;
  };

#define SBAR __builtin_amdgcn_sched_barrier(0)
  LOAD(0,B0); LOAD(1,B1); LOAD(2,B2); LOAD(3,B3);
  LOAD(4,B4); LOAD(5,B5); LOAD(6,B6);
  SBAR;
  for (int t=0; t<TT; t+=8){
    LOAD(t+ 7 < TT ? t+ 7 : TT-1, B7); SBAR; STEP(B0, t);   SBAR;
    LOAD(t+ 8 < TT ? t+ 8 : TT-1, B0); SBAR; STEP(B1, t+1); SBAR;
    LOAD(t+ 9 < TT ? t+ 9 : TT-1, B1); SBAR; STEP(B2, t+2); SBAR;
    LOAD(t+10 < TT ? t+10 : TT-1, B2); SBAR; STEP(B3, t+3); SBAR;
    LOAD(t+11 < TT ? t+11 : TT-1, B3); SBAR; STEP(B4, t+4); SBAR;
    LOAD(t+12 < TT ? t+12 : TT-1, B4); SBAR; STEP(B5, t+5); SBAR;
    LOAD(t+13 < TT ? t+13 : TT-1, B5); SBAR; STEP(B6, t+6); SBAR;
    LOAD(t+14 < TT ? t+14 : TT-1, B6); SBAR; STEP(B7, t+7); SBAR;
  }
#undef SBAR
}

// ---------------- y1 = x + proj*sigmoid(gate_pre) --------------------------
__global__ __launch_bounds__(256) void gate_comb(
    const float* __restrict__ x, const float* __restrict__ p,
    const float* __restrict__ g, float* __restrict__ y1)
{
  size_t i = ((size_t)blockIdx.x*256 + threadIdx.x)*4;
  f32x4 xv = *(const f32x4*)(x+i);
  f32x4 pv = *(const f32x4*)(p+i);
  f32x4 gv = *(const f32x4*)(g+i);
  f32x4 o;
  o.x = xv.x + pv.x * sigm(gv.x);
  o.y = xv.y + pv.y * sigm(gv.y);
  o.z = xv.z + pv.z * sigm(gv.z);
  o.w = xv.w + pv.w * sigm(gv.w);
  *(f32x4*)(y1+i) = o;
}

// ---------------- z = bf16(y1 * invr * ff_norm_w) --------------------------
__global__ __launch_bounds__(256) void zscale(
    const float* __restrict__ y1, const float* __restrict__ invr,
    const float* __restrict__ w, u16* __restrict__ z)
{
  int m = blockIdx.x; int d4 = threadIdx.x*4;
  float sc = invr[m];
  f32x4 v = *(const f32x4*)(y1 + (size_t)m*DD + d4);
  f32x4 wv = *(const f32x4*)(w + d4);
  u16x4 o; o.x=f2b(v.x*sc*wv.x); o.y=f2b(v.y*sc*wv.y); o.z=f2b(v.z*sc*wv.z); o.w=f2b(v.w*sc*wv.w);
  *(u16x4*)(z + (size_t)m*DD + d4) = o;
}

// ---------------- ffh = bf16(silu(h1) * h3) over one M-chunk ---------------
__global__ __launch_bounds__(256) void ffn_comb(
    const float* __restrict__ ffa2, u16* __restrict__ ffh)
{
  size_t i = ((size_t)blockIdx.x*256 + threadIdx.x)*4;   // over 1024*4096
  int m = (int)(i >> 12), j = (int)(i & 4095);
  f32x4 a = *(const f32x4*)(ffa2 + (size_t)m*8192 + j);
  f32x4 bq = *(const f32x4*)(ffa2 + (size_t)m*8192 + 4096 + j);
  u16x4 o;
  o.x = f2b(silu_f(a.x)*bq.x); o.y = f2b(silu_f(a.y)*bq.y);
  o.z = f2b(silu_f(a.z)*bq.z); o.w = f2b(silu_f(a.w)*bq.w);
  *(u16x4*)(ffh + i) = o;
}

extern "C" void kernel_launch(void* const* d_in, const int* in_sizes, int n_in,
                              void* d_out, int out_size, void* d_ws, size_t ws_size,
                              hipStream_t stream)
{
  (void)in_sizes; (void)n_in; (void)out_size; (void)ws_size;
  const float* x    = (const float*)d_in[0];
  const float* st0  = (const float*)d_in[1];
  const float* mem0 = (const float*)d_in[2];
  const float* nin  = (const float*)d_in[3];
  const float* cw   = (const float*)d_in[4];
  const float* cb   = (const float*)d_in[5];
  const float* qw   = (const float*)d_in[6];
  const float* kw   = (const float*)d_in[7];
  const float* vw   = (const float*)d_in[8];
  const float* ow   = (const float*)d_in[9];
  const float* sw   = (const float*)d_in[10];
  const float* aupw = (const float*)d_in[11];
  const float* aupb = (const float*)d_in[12];
  const float* adnw = (const float*)d_in[13];
  const float* adnb = (const float*)d_in[14];
  const float* aspk = (const float*)d_in[15];
  const float* betw = (const float*)d_in[16];
  const float* betb = (const float*)d_in[17];
  const float* bspk = (const float*)d_in[18];
  const float* hnw  = (const float*)d_in[19];
  const float* u1w  = (const float*)d_in[20];
  const float* u1b  = (const float*)d_in[21];
  const float* u2w  = (const float*)d_in[22];
  const float* u2b  = (const float*)d_in[23];
  const float* ffnw = (const float*)d_in[24];
  const float* fw1  = (const float*)d_in[25];
  const float* fw3  = (const float*)d_in[26];
  const float* fw2  = (const float*)d_in[27];
  float* out = (float*)d_out;

  char* wsb = (char*)d_ws;
  size_t off = 0;
  auto alloc = [&](size_t bytes)->char*{
    off = (off + 255) & ~(size_t)255;
    char* p = wsb + off; off += bytes; return p;
  };

  // persistent
  u16* wcat4 = (u16*)alloc((size_t)4096*DD*2);   // [qw;kw;vw;sw_hi]
  u16* swcat = (u16*)alloc((size_t)DD*2048*2);   // [swlo | swhi]
  u16* owb   = (u16*)alloc((size_t)DD*DD*2);
  u16* fwcat = (u16*)alloc((size_t)2*DFF*DD*2);  // [fw1; fw3]
  u16* fw2b  = (u16*)alloc((size_t)DD*DFF*2);
  u16* aupwb = (u16*)alloc((size_t)128*DD*2);
  u16* adnwb = (u16*)alloc((size_t)DD*128*2);
  u16* betwb = (u16*)alloc((size_t)128*DD*2);
  u16* u1wb  = (u16*)alloc((size_t)128*DD*2);
  u16* u2wb  = (u16*)alloc((size_t)DD*128*2);
  float* aupbp = (float*)alloc(128*4);
  float* betbp = (float*)alloc(128*4);
  float* u1bp  = (float*)alloc(128*4);
  u16* xbf  = (u16*)alloc((size_t)MM*DD*2);
  float* yatt  = (float*)alloc((size_t)MM*DD*4);
  u16* yattb = (u16*)alloc((size_t)MM*DD*2);
  float* invr  = (float*)alloc((size_t)MM*4);

  // early region
  size_t mark = off;
  u16* hcat = (u16*)alloc((size_t)MM*2048*2);    // [h_bf16 | h_lo]
  float* qkvd = (float*)alloc((size_t)MM*SKQ*4); // [q|k|v|drive]
  float* abase = (float*)alloc((size_t)MM*DD*4); // becomes alpha in place
  float* bbase = (float*)alloc((size_t)MM*128*4);
  float* bscale= (float*)alloc((size_t)MM*8*4);
  u64* spk = (u64*)alloc((size_t)BB*HH*TT*2*8);
  u16* gsm  = (u16*)alloc((size_t)MM*128*2);
  // late region (aliases early)
  off = mark;
  float* proj = (float*)alloc((size_t)MM*DD*4);
  float* gpre = (float*)alloc((size_t)MM*DD*4);
  u16* zbf  = (u16*)alloc((size_t)MM*DD*2);
  u16* g1   = (u16*)alloc((size_t)MM*128*2);
  float* ffa2 = (float*)alloc((size_t)1024*2*DFF*4);
  u16* ffh  = (u16*)alloc((size_t)MM*DFF*2);

  dim3 blk(256);

  prep_all<<<dim3(22145), blk, 0, stream>>>(
      qw, kw, vw, sw, ow, fw1, fw3, fw2, x, aupw, adnw, betw, u1w, u2w,
      aupb, betb, u1b,
      wcat4, swcat, owb, fwcat, fw2b, xbf, aupwb, adnwb, betwb, u1wb, u2wb,
      aupbp, betbp, u1bp);

  // norm + conv + silu
  row_rms<<<dim3(MM), blk, 0, stream>>>(x, invr);
  conv_silu_k<<<dim3(MM), blk, 0, stream>>>(x, invr, nin, cw, cb, hcat);

  // fused q|k|v|drive_hi projection  (grid 32x32 = 1024 wg -> 2 blocks/CU)
  gemm_bt<0><<<dim3(32,32), blk, 0, stream>>>(hcat, wcat4, qkvd, nullptr, nullptr,
                                              4096, DD, 2048, DD, SKQ);
  // drive lo fix: qkvd[:,3072:4096] += [hbf|hlo] @ [swlo|swhi]  (K=2048)
  gemm_bt<1><<<dim3(32,8), blk, 0, stream>>>(hcat, swcat, qkvd+3072, nullptr, nullptr,
                                             DD, 2048, 2048, 2048, SKQ);
  // beta base [M,128]
  gemm_bt<0><<<dim3(32,1), blk, 0, stream>>>(hcat, betwb, bbase, nullptr, betbp,
                                             128, DD, 2048, DD, 128);
  // LIF spike scan (reads drive from qkvd+3072)
  spike_scan<<<dim3(BB*HH), dim3(64), 0, stream>>>(qkvd+3072, bbase, bspk, mem0, spk, bscale);
  // alpha base: silu(h@up+b) @ down + b
  gemm_bt<2><<<dim3(32,1), blk, 0, stream>>>(hcat, aupwb, nullptr, gsm, aupbp,
                                             128, DD, 2048, DD, 128);
  gemm_bt<0><<<dim3(32,8), blk, 0, stream>>>(gsm, adnwb, abase, nullptr, adnb,
                                             DD, 128, 128, 128, DD);
  alpha_apply<<<dim3(MM), blk, 0, stream>>>(abase, spk, aspk);

  qk_norm<<<dim3(MM*HH/4), blk, 0, stream>>>(qkvd);
  scan_k<<<dim3(BB*HH*8), blk, 0, stream>>>(qkvd, abase, bscale, st0, yatt);
  head_norm_k<<<dim3(MM*HH/4), blk, 0, stream>>>(yatt, hnw, yattb);

  // out proj, gate, combine
  gemm_bt<0><<<dim3(32,8), blk, 0, stream>>>(yattb, owb, proj, nullptr, nullptr,
                                             DD, DD, DD, DD, DD);
  gemm_bt<2><<<dim3(32,1), blk, 0, stream>>>(xbf, u1wb, nullptr, g1, u1bp,
                                             128, DD, DD, DD, 128);
  gemm_bt<0><<<dim3(32,8), blk, 0, stream>>>(g1, u2wb, gpre, nullptr, u2b,
                                             DD, 128, 128, 128, DD);
  gate_comb<<<dim3(MM*DD/1024), blk, 0, stream>>>(x, proj, gpre, out);

  // FFN
  row_rms<<<dim3(MM), blk, 0, stream>>>(out, invr);
  zscale<<<dim3(MM), blk, 0, stream>>>(out, invr, ffnw, zbf);
  for (int c=0; c<4; ++c) {
    const u16* zc = zbf + (size_t)c*1024*DD;
    gemm_bt<0><<<dim3(8,64), blk, 0, stream>>>(zc, fwcat, ffa2, nullptr, nullptr,
                                               2*DFF, DD, DD, DD, 2*DFF);
    ffn_comb<<<dim3(4096), blk, 0, stream>>>(ffa2, ffh + (size_t)c*1024*DFF);
  }
  gemm_bt<1><<<dim3(32,8), blk, 0, stream>>>(ffh, fw2b, out, nullptr, nullptr,
                                             DD, DFF, DFF, DFF, DD);
}